// Round 1
// baseline (184.908 us; speedup 1.0000x reference)
//
#include <hip/hip_runtime.h>
#include <stdint.h>

// HypergraphConv: B=8, N=2048, E=1024, Fin=Fout=256, fp32 in/out.
// out = relu( Dv^-1 * H @ (De^-1 * (H^T @ (x@W))) )
// Pipeline: k_prep (H->bf16 + Dv/De sums) -> GEMM1 (xw) -> GEMM2 (HTX, *De^-1)
//           -> GEMM3 (H@Y, *Dv^-1, relu).

typedef __bf16 bf16x8 __attribute__((ext_vector_type(8)));
typedef float f32x4 __attribute__((ext_vector_type(4)));

#define LDSP 40  // padded LDS row stride in elements (32 + 8)

__device__ __forceinline__ uint16_t f2b(float f) {
  union { float f; uint32_t u; } v; v.f = f;
  return (uint16_t)((v.u + 0x7FFFu + ((v.u >> 16) & 1u)) >> 16);  // RNE
}

__device__ __forceinline__ f32x4 mfma16(bf16x8 a, bf16x8 b, f32x4 c) {
  return __builtin_amdgcn_mfma_f32_16x16x32_bf16(a, b, c, 0, 0, 0);
}

__device__ __forceinline__ bf16x8 ldsfrag(const uint16_t* p) {
  return *(const bf16x8*)p;  // 16B-aligned ds_read_b128
}

// ---- prep: H fp32 -> bf16; Dv[b,n] = sum_e H; De[b,e] = sum_n H ----
__global__ __launch_bounds__(256) void k_prep(const float* __restrict__ H,
    uint16_t* __restrict__ Hb, float* __restrict__ Dv, float* __restrict__ De) {
  const int NN = 2048, EE = 1024;
  const int b  = blockIdx.y;
  const int n0 = blockIdx.x * 16;
  const int t  = threadIdx.x;
  const int lane = t & 63;
  const size_t base = ((size_t)b * NN + n0) * EE;
  float de0 = 0.f, de1 = 0.f, de2 = 0.f, de3 = 0.f;
  for (int r = 0; r < 16; ++r) {
    float4 v = *(const float4*)(H + base + (size_t)r * EE + 4 * t);
    union { uint16_t s[4]; uint2 q; } pk;
    pk.s[0] = f2b(v.x); pk.s[1] = f2b(v.y); pk.s[2] = f2b(v.z); pk.s[3] = f2b(v.w);
    *(uint2*)(Hb + base + (size_t)r * EE + 4 * t) = pk.q;
    de0 += v.x; de1 += v.y; de2 += v.z; de3 += v.w;
    float rs = (v.x + v.y) + (v.z + v.w);
    #pragma unroll
    for (int off = 32; off > 0; off >>= 1) rs += __shfl_down(rs, off);
    if (lane == 0) atomicAdd(&Dv[b * NN + n0 + r], rs);
  }
  float* dep = De + b * EE + 4 * t;
  atomicAdd(dep + 0, de0); atomicAdd(dep + 1, de1);
  atomicAdd(dep + 2, de2); atomicAdd(dep + 3, de3);
}

// ---- GEMM1: XWb[m][f] = bf16( X[m][k] @ W[k][f] ), M=16384, K=F=256 ----
__global__ __launch_bounds__(256) void k_gemm1(const float* __restrict__ X,
    const float* __restrict__ W, uint16_t* __restrict__ XWb) {
  const int K = 256, F = 256;
  __shared__ __align__(16) uint16_t As[64 * LDSP];
  __shared__ __align__(16) uint16_t Bs[64 * LDSP];
  const int m0 = blockIdx.y * 64;
  const int f0 = blockIdx.x * 64;
  const int t = threadIdx.x;
  const int lane = t & 63;
  const int wave = t >> 6;
  const int l15 = lane & 15;
  const int kg  = (lane >> 4) * 8;
  const int wm = (wave >> 1) * 32;
  const int wn = (wave & 1) * 32;
  f32x4 acc[2][2] = {};
  for (int k0 = 0; k0 < K; k0 += 32) {
    {  // A stage: 64 rows x 32 k, fp32 -> bf16, row-major
      const int r = t >> 2, c = (t & 3) * 8;
      const float* src = X + (size_t)(m0 + r) * K + k0 + c;
      float4 v0 = *(const float4*)src;
      float4 v1 = *(const float4*)(src + 4);
      union { uint16_t s[8]; uint4 q; } p;
      p.s[0] = f2b(v0.x); p.s[1] = f2b(v0.y); p.s[2] = f2b(v0.z); p.s[3] = f2b(v0.w);
      p.s[4] = f2b(v1.x); p.s[5] = f2b(v1.y); p.s[6] = f2b(v1.z); p.s[7] = f2b(v1.w);
      *(uint4*)&As[r * LDSP + c] = p.q;
    }
    {  // B stage transposed: Bs[f][k] <- W[k][f]
      #pragma unroll
      for (int it = 0; it < 2; ++it) {
        const int kk = (t >> 4) + it * 16;
        const int fc = (t & 15) * 4;
        float4 v = *(const float4*)(W + (size_t)(k0 + kk) * F + f0 + fc);
        Bs[(fc + 0) * LDSP + kk] = f2b(v.x);
        Bs[(fc + 1) * LDSP + kk] = f2b(v.y);
        Bs[(fc + 2) * LDSP + kk] = f2b(v.z);
        Bs[(fc + 3) * LDSP + kk] = f2b(v.w);
      }
    }
    __syncthreads();
    bf16x8 a0 = ldsfrag(&As[(wm + l15) * LDSP + kg]);
    bf16x8 a1 = ldsfrag(&As[(wm + 16 + l15) * LDSP + kg]);
    bf16x8 b0 = ldsfrag(&Bs[(wn + l15) * LDSP + kg]);
    bf16x8 b1 = ldsfrag(&Bs[(wn + 16 + l15) * LDSP + kg]);
    acc[0][0] = mfma16(a0, b0, acc[0][0]);
    acc[0][1] = mfma16(a0, b1, acc[0][1]);
    acc[1][0] = mfma16(a1, b0, acc[1][0]);
    acc[1][1] = mfma16(a1, b1, acc[1][1]);
    __syncthreads();
  }
  const int rbase = (lane >> 4) * 4;
  #pragma unroll
  for (int i = 0; i < 2; ++i)
    #pragma unroll
    for (int j = 0; j < 2; ++j)
      #pragma unroll
      for (int reg = 0; reg < 4; ++reg) {
        const int row = m0 + wm + i * 16 + rbase + reg;
        const int col = f0 + wn + j * 16 + l15;
        XWb[(size_t)row * F + col] = f2b(acc[i][j][reg]);
      }
}

// ---- GEMM2: Yb[b][e][f] = bf16( De^-1[b,e] * sum_n H[b,n,e]*xw[b,n,f] ) ----
__global__ __launch_bounds__(256) void k_gemm2(const uint16_t* __restrict__ Hb,
    const uint16_t* __restrict__ XWb, const float* __restrict__ De,
    uint16_t* __restrict__ Yb) {
  const int N = 2048, E = 1024, F = 256;
  __shared__ __align__(16) uint16_t As[64 * LDSP];
  __shared__ __align__(16) uint16_t Bs[64 * LDSP];
  const int b  = blockIdx.z;
  const int e0 = blockIdx.y * 64;
  const int f0 = blockIdx.x * 64;
  const int t = threadIdx.x;
  const int lane = t & 63;
  const int wave = t >> 6;
  const int l15 = lane & 15;
  const int kg  = (lane >> 4) * 8;
  const int wm = (wave >> 1) * 32;
  const int wn = (wave & 1) * 32;
  const uint16_t* Hbb  = Hb  + (size_t)b * N * E;
  const uint16_t* XWbb = XWb + (size_t)b * N * F;
  f32x4 acc[2][2] = {};
  for (int n0 = 0; n0 < N; n0 += 32) {
    {  // A: As[e_loc][n_loc] (transpose from H[n][e], e contiguous)
      const int nn = t >> 3, eo = (t & 7) * 8;
      union { uint16_t s[8]; uint4 q; } p;
      p.q = *(const uint4*)(Hbb + (size_t)(n0 + nn) * E + e0 + eo);
      #pragma unroll
      for (int j = 0; j < 8; ++j) As[(eo + j) * LDSP + nn] = p.s[j];
    }
    {  // B: Bs[f_loc][n_loc] (transpose from xw[n][f])
      const int nn = t >> 3, fo = (t & 7) * 8;
      union { uint16_t s[8]; uint4 q; } p;
      p.q = *(const uint4*)(XWbb + (size_t)(n0 + nn) * F + f0 + fo);
      #pragma unroll
      for (int j = 0; j < 8; ++j) Bs[(fo + j) * LDSP + nn] = p.s[j];
    }
    __syncthreads();
    bf16x8 a0 = ldsfrag(&As[(wm + l15) * LDSP + kg]);
    bf16x8 a1 = ldsfrag(&As[(wm + 16 + l15) * LDSP + kg]);
    bf16x8 b0 = ldsfrag(&Bs[(wn + l15) * LDSP + kg]);
    bf16x8 b1 = ldsfrag(&Bs[(wn + 16 + l15) * LDSP + kg]);
    acc[0][0] = mfma16(a0, b0, acc[0][0]);
    acc[0][1] = mfma16(a0, b1, acc[0][1]);
    acc[1][0] = mfma16(a1, b0, acc[1][0]);
    acc[1][1] = mfma16(a1, b1, acc[1][1]);
    __syncthreads();
  }
  const int rbase = (lane >> 4) * 4;
  #pragma unroll
  for (int i = 0; i < 2; ++i)
    #pragma unroll
    for (int j = 0; j < 2; ++j) {
      #pragma unroll
      for (int reg = 0; reg < 4; ++reg) {
        const int er = e0 + wm + i * 16 + rbase + reg;
        const float sc = 1.0f / (De[b * E + er] + 1e-9f);
        Yb[(size_t)b * E * F + (size_t)er * F + f0 + wn + j * 16 + l15] =
            f2b(acc[i][j][reg] * sc);
      }
    }
}

// ---- GEMM3: out[b][n][f] = relu( Dv^-1[b,n] * sum_e H[b,n,e]*Y[b,e,f] ) ----
__global__ __launch_bounds__(256) void k_gemm3(const uint16_t* __restrict__ Hb,
    const uint16_t* __restrict__ Yb, const float* __restrict__ Dv,
    float* __restrict__ out) {
  const int N = 2048, E = 1024, F = 256;
  __shared__ __align__(16) uint16_t As[64 * LDSP];
  __shared__ __align__(16) uint16_t Bs[64 * LDSP];
  const int b  = blockIdx.z;
  const int n0 = blockIdx.y * 64;
  const int f0 = blockIdx.x * 64;
  const int t = threadIdx.x;
  const int lane = t & 63;
  const int wave = t >> 6;
  const int l15 = lane & 15;
  const int kg  = (lane >> 4) * 8;
  const int wm = (wave >> 1) * 32;
  const int wn = (wave & 1) * 32;
  const uint16_t* Hbb = Hb + (size_t)b * N * E;
  const uint16_t* Ybb = Yb + (size_t)b * E * F;
  f32x4 acc[2][2] = {};
  for (int e0 = 0; e0 < E; e0 += 32) {
    {  // A direct: As[n_loc][e_loc] from H[n][e] (e contiguous = k)
      const int r = t >> 2, c = (t & 3) * 8;
      *(uint4*)&As[r * LDSP + c] =
          *(const uint4*)(Hbb + (size_t)(n0 + r) * E + e0 + c);
    }
    {  // B: Bs[f_loc][e_loc] (transpose from Y[e][f])
      const int ee = t >> 3, fo = (t & 7) * 8;
      union { uint16_t s[8]; uint4 q; } p;
      p.q = *(const uint4*)(Ybb + (size_t)(e0 + ee) * F + f0 + fo);
      #pragma unroll
      for (int j = 0; j < 8; ++j) Bs[(fo + j) * LDSP + ee] = p.s[j];
    }
    __syncthreads();
    bf16x8 a0 = ldsfrag(&As[(wm + l15) * LDSP + kg]);
    bf16x8 a1 = ldsfrag(&As[(wm + 16 + l15) * LDSP + kg]);
    bf16x8 b0 = ldsfrag(&Bs[(wn + l15) * LDSP + kg]);
    bf16x8 b1 = ldsfrag(&Bs[(wn + 16 + l15) * LDSP + kg]);
    acc[0][0] = mfma16(a0, b0, acc[0][0]);
    acc[0][1] = mfma16(a0, b1, acc[0][1]);
    acc[1][0] = mfma16(a1, b0, acc[1][0]);
    acc[1][1] = mfma16(a1, b1, acc[1][1]);
    __syncthreads();
  }
  const int rbase = (lane >> 4) * 4;
  #pragma unroll
  for (int i = 0; i < 2; ++i)
    #pragma unroll
    for (int j = 0; j < 2; ++j) {
      #pragma unroll
      for (int reg = 0; reg < 4; ++reg) {
        const int nr = n0 + wm + i * 16 + rbase + reg;
        const float sc = 1.0f / (Dv[b * N + nr] + 1e-9f);
        float val = acc[i][j][reg] * sc;
        out[(size_t)b * N * F + (size_t)nr * F + f0 + wn + j * 16 + l15] =
            val > 0.f ? val : 0.f;
      }
    }
}

extern "C" void kernel_launch(void* const* d_in, const int* in_sizes, int n_in,
                              void* d_out, int out_size, void* d_ws, size_t ws_size,
                              hipStream_t stream) {
  (void)in_sizes; (void)n_in; (void)out_size;
  const float* x = (const float*)d_in[0];   // [8,2048,256]
  const float* H = (const float*)d_in[1];   // [8,2048,1024]
  const float* W = (const float*)d_in[2];   // [256,256]
  float* out = (float*)d_out;               // [8,2048,256]

  // workspace layout (bytes):
  //   Hb  bf16 [8,2048,1024] : 0        .. 33554432
  //   XWb bf16 [8,2048,256]  : 33554432 .. 41943040
  //   Yb  bf16 [8,1024,256]  : 41943040 .. 46137344
  //   Dv  f32  [8,2048]      : 46137344 .. 46202880
  //   De  f32  [8,1024]      : 46202880 .. 46235648
  if (ws_size < 46235648) return;
  char* ws = (char*)d_ws;
  uint16_t* Hb  = (uint16_t*)(ws);
  uint16_t* XWb = (uint16_t*)(ws + 33554432);
  uint16_t* Yb  = (uint16_t*)(ws + 41943040);
  float*    Dv  = (float*)(ws + 46137344);
  float*    De  = (float*)(ws + 46202880);

  hipMemsetAsync(Dv, 0, 98304, stream);  // zero Dv+De (contiguous)
  k_prep <<<dim3(128, 8),    256, 0, stream>>>(H, Hb, Dv, De);
  k_gemm1<<<dim3(4, 256),    256, 0, stream>>>(x, W, XWb);
  k_gemm2<<<dim3(4, 16, 8),  256, 0, stream>>>(Hb, XWb, De, Yb);
  k_gemm3<<<dim3(4, 32, 8),  256, 0, stream>>>(Hb, Yb, Dv, out);
}

// Round 2
// 130.571 us; speedup vs baseline: 1.4161x; 1.4161x over previous
//
#include <hip/hip_runtime.h>
#include <stdint.h>

// HypergraphConv: B=8, N=2048, E=1024, Fin=Fout=256, fp32 in/out.
// out = relu( Dv^-1 * H @ (De^-1 * (H^T @ (x@W))) )
// All-k-contiguous layouts:
//   prep : H -> Hbt[b][e][n] bf16 (+ Dv,De sums)
//   gemm1: XWt[b][f][n] = bf16((x@W)^T)          A=W^T (LDS transp), B=x (f32 stage)
//   gemm2: Yt[b][f][e] = bf16(De^-1 * XWt@Hbt^T) both operands global_load_lds+XOR swz
//   gemm3: out[b][n][f] = relu(Dv^-1 * H@Yt^T)   A=H f32 stage, B=Yt gload_lds
// 2-phase double-buffered K-loop (stage next || compute current), BK=64.

typedef __bf16 bf16x8 __attribute__((ext_vector_type(8)));
typedef float f32x4 __attribute__((ext_vector_type(4)));

#define PADK 72  // padded row stride (elems) for f32-reg-staged tiles

__device__ __forceinline__ uint16_t f2b(float f) {
  union { float f; uint32_t u; } v; v.f = f;
  return (uint16_t)((v.u + 0x7FFFu + ((v.u >> 16) & 1u)) >> 16);  // RNE
}

__device__ __forceinline__ f32x4 mfma16(bf16x8 a, bf16x8 b, f32x4 c) {
  return __builtin_amdgcn_mfma_f32_16x16x32_bf16(a, b, c, 0, 0, 0);
}

// async global->LDS, 16B/lane; LDS dest = uniform base + lane*16
__device__ __forceinline__ void gload16(const void* src, void* dst) {
  __builtin_amdgcn_global_load_lds(
      (const __attribute__((address_space(1))) void*)src,
      (__attribute__((address_space(3))) void*)dst, 16, 0, 0);
}

// ---- prep: Hbt[b][e][n] = bf16(H[b][n][e]); Dv row sums; De col sums ----
__global__ __launch_bounds__(256) void k_prep_h(const float* __restrict__ H,
    uint16_t* __restrict__ Hbt, float* __restrict__ Dv, float* __restrict__ De) {
  __shared__ __align__(8) uint16_t T[64][PADK];
  __shared__ float csum[64];
  const int n0 = blockIdx.x * 64, e0 = blockIdx.y * 64, b = blockIdx.z;
  const int t = threadIdx.x;
  if (t < 64) csum[t] = 0.f;
  __syncthreads();
  const int rr = t >> 4, cc = (t & 15) * 4;
  float de[4] = {0.f, 0.f, 0.f, 0.f};
  #pragma unroll
  for (int i = 0; i < 4; ++i) {
    const int r = rr + i * 16;
    float4 v = *(const float4*)(H + ((size_t)b * 2048 + n0 + r) * 1024 + e0 + cc);
    union { uint16_t s[4]; uint2 q; } p;
    p.s[0] = f2b(v.x); p.s[1] = f2b(v.y); p.s[2] = f2b(v.z); p.s[3] = f2b(v.w);
    *(uint2*)&T[r][cc] = p.q;
    de[0] += v.x; de[1] += v.y; de[2] += v.z; de[3] += v.w;
    float rs = (v.x + v.y) + (v.z + v.w);
    rs += __shfl_xor(rs, 1); rs += __shfl_xor(rs, 2);
    rs += __shfl_xor(rs, 4); rs += __shfl_xor(rs, 8);
    if ((t & 15) == 0) atomicAdd(&Dv[b * 2048 + n0 + r], rs);
  }
  #pragma unroll
  for (int j = 0; j < 4; ++j) atomicAdd(&csum[cc + j], de[j]);
  __syncthreads();
  if (t < 64) atomicAdd(&De[b * 1024 + e0 + t], csum[t]);
  // transposed store: row e' = t>>2, 16-wide n chunk = (t&3)*16
  const int ep = t >> 2, nc = (t & 3) * 16;
  union { uint16_t s[16]; uint4 q[2]; } o;
  #pragma unroll
  for (int j = 0; j < 16; ++j) o.s[j] = T[nc + j][ep];
  uint16_t* dst = Hbt + ((size_t)b * 1024 + e0 + ep) * 2048 + n0 + nc;
  *(uint4*)dst = o.q[0];
  *(uint4*)(dst + 8) = o.q[1];
}

// ---- GEMM1: XWt[b][f][n] = bf16( sum_k W[k][f] * x[b][n][k] ) ----
// tile 128f x 128n, K=256, BK=64
__global__ __launch_bounds__(256) void k_gemm1(const float* __restrict__ X,
    const float* __restrict__ W, uint16_t* __restrict__ XWt) {
  __shared__ __align__(16) uint16_t As[2][128 * PADK];
  __shared__ __align__(16) uint16_t Bs[2][128 * PADK];
  const int n0 = blockIdx.x * 128, f0 = blockIdx.y * 128, b = blockIdx.z;
  const int t = threadIdx.x, lane = t & 63, wave = t >> 6;
  const int l15 = lane & 15, lq = lane >> 4;
  // A stage (W^T): thread reads k-row wr, 32 f at wc; writes transposed scalar
  const int wr = t >> 2, wc = (t & 3) * 32;
  // B stage (x): thread reads n-row brow, 32 k at bc0
  const int brow = t >> 1, bc0 = (t & 1) * 32;
  const float* Wg = W + (size_t)wr * 256 + f0 + wc;
  const float* Xg = X + ((size_t)b * 2048 + n0 + brow) * 256 + bc0;
  float4 RW[8], RX[8];
  auto gloadA = [&](int kt) {
    const float* s = Wg + (size_t)kt * 64 * 256;
    #pragma unroll
    for (int q = 0; q < 8; ++q) RW[q] = *(const float4*)(s + q * 4);
  };
  auto gloadB = [&](int kt) {
    const float* s = Xg + kt * 64;
    #pragma unroll
    for (int q = 0; q < 8; ++q) RX[q] = *(const float4*)(s + q * 4);
  };
  auto writeA = [&](uint16_t* Ad) {
    const float* f = (const float*)RW;
    #pragma unroll
    for (int j = 0; j < 32; ++j) Ad[(wc + j) * PADK + wr] = f2b(f[j]);
  };
  auto writeB = [&](uint16_t* Bd) {
    uint16_t* d = Bd + brow * PADK + bc0;
    const float* f = (const float*)RX;
    #pragma unroll
    for (int q = 0; q < 4; ++q) {
      union { uint16_t s[8]; uint4 u; } p;
      #pragma unroll
      for (int j = 0; j < 8; ++j) p.s[j] = f2b(f[q * 8 + j]);
      *(uint4*)(d + q * 8) = p.u;
    }
  };
  f32x4 acc[4][4] = {};
  auto compute = [&](const uint16_t* Ad, const uint16_t* Bd) {
    #pragma unroll
    for (int h = 0; h < 2; ++h) {
      bf16x8 af[4], bf[4];
      #pragma unroll
      for (int i = 0; i < 4; ++i)
        af[i] = *(const bf16x8*)(Ad + ((wave >> 1) * 64 + i * 16 + l15) * PADK + h * 32 + lq * 8);
      #pragma unroll
      for (int j = 0; j < 4; ++j)
        bf[j] = *(const bf16x8*)(Bd + ((wave & 1) * 64 + j * 16 + l15) * PADK + h * 32 + lq * 8);
      #pragma unroll
      for (int i = 0; i < 4; ++i)
        #pragma unroll
        for (int j = 0; j < 4; ++j)
          acc[i][j] = mfma16(af[i], bf[j], acc[i][j]);
    }
  };
  gloadA(0); gloadB(0); writeA(As[0]); writeB(Bs[0]);
  __syncthreads();
  for (int kt = 0; kt < 4; kt += 2) {
    gloadA(kt + 1); gloadB(kt + 1);
    compute(As[0], Bs[0]);
    writeA(As[1]); writeB(Bs[1]);
    __syncthreads();
    if (kt + 2 < 4) { gloadA(kt + 2); gloadB(kt + 2); }
    compute(As[1], Bs[1]);
    if (kt + 2 < 4) { writeA(As[0]); writeB(Bs[0]); }
    __syncthreads();
  }
  #pragma unroll
  for (int i = 0; i < 4; ++i) {
    const int fr = f0 + (wave >> 1) * 64 + i * 16 + lq * 4;
    #pragma unroll
    for (int j = 0; j < 4; ++j) {
      const int col = n0 + (wave & 1) * 64 + j * 16 + l15;
      #pragma unroll
      for (int reg = 0; reg < 4; ++reg)
        XWt[((size_t)b * 256 + fr + reg) * 2048 + col] = f2b(acc[i][j][reg]);
    }
  }
}

// ---- GEMM2: Yt[b][f][e] = bf16( De^-1[b,e] * sum_n XWt[f][n]*Hbt[e][n] ) ----
// tile 64f x 128e, K=2048, BK=64; both operands gload_lds + XOR swizzle
__global__ __launch_bounds__(256) void k_gemm2(const uint16_t* __restrict__ Hbt,
    const uint16_t* __restrict__ XWt, const float* __restrict__ De,
    uint16_t* __restrict__ Yt) {
  __shared__ __align__(16) uint16_t As[2][64 * 64];
  __shared__ __align__(16) uint16_t Bs[2][128 * 64];
  const int e0 = blockIdx.x * 128, f0 = blockIdx.y * 64, b = blockIdx.z;
  const int t = threadIdx.x, lane = t & 63, wave = t >> 6;
  const int l15 = lane & 15, lq = lane >> 4;
  const int rlane = lane >> 3;
  const int srcswz = ((lane & 7) ^ rlane) << 3;  // source 16B-block permutation
  const uint16_t* Ag = XWt + ((size_t)b * 256 + f0) * 2048;
  const uint16_t* Bg = Hbt + ((size_t)b * 1024 + e0) * 2048;
  auto stage = [&](uint16_t* Ad, uint16_t* Bd, int kt) {
    const int k0 = kt * 64;
    int rb = wave * 16;
    gload16(Ag + (size_t)(rb + rlane) * 2048 + k0 + srcswz, Ad + rb * 64);
    gload16(Ag + (size_t)(rb + 8 + rlane) * 2048 + k0 + srcswz, Ad + (rb + 8) * 64);
    #pragma unroll
    for (int i = 0; i < 4; ++i) {
      int rB = wave * 32 + i * 8;
      gload16(Bg + (size_t)(rB + rlane) * 2048 + k0 + srcswz, Bd + rB * 64);
    }
  };
  f32x4 acc[2][4] = {};
  auto compute = [&](const uint16_t* Ad, const uint16_t* Bd) {
    #pragma unroll
    for (int h = 0; h < 2; ++h) {
      bf16x8 af[2], bf[4];
      #pragma unroll
      for (int i = 0; i < 2; ++i) {
        const int r = (wave >> 1) * 32 + i * 16 + l15;
        af[i] = *(const bf16x8*)(Ad + r * 64 + ((((h << 2) | lq) ^ (r & 7)) << 3));
      }
      #pragma unroll
      for (int j = 0; j < 4; ++j) {
        const int r = (wave & 1) * 64 + j * 16 + l15;
        bf[j] = *(const bf16x8*)(Bd + r * 64 + ((((h << 2) | lq) ^ (r & 7)) << 3));
      }
      #pragma unroll
      for (int i = 0; i < 2; ++i)
        #pragma unroll
        for (int j = 0; j < 4; ++j)
          acc[i][j] = mfma16(af[i], bf[j], acc[i][j]);
    }
  };
  stage(As[0], Bs[0], 0);
  __syncthreads();
  for (int kt = 0; kt < 32; kt += 2) {
    stage(As[1], Bs[1], kt + 1);
    compute(As[0], Bs[0]);
    __syncthreads();
    if (kt + 2 < 32) stage(As[0], Bs[0], kt + 2);
    compute(As[1], Bs[1]);
    __syncthreads();
  }
  #pragma unroll
  for (int i = 0; i < 2; ++i) {
    const int fr = f0 + (wave >> 1) * 32 + i * 16 + lq * 4;
    #pragma unroll
    for (int j = 0; j < 4; ++j) {
      const int e = e0 + (wave & 1) * 64 + j * 16 + l15;
      const float sc = 1.0f / (De[b * 1024 + e] + 1e-9f);
      uint16_t* dst = Yt + ((size_t)b * 256 + fr) * 1024 + e;
      #pragma unroll
      for (int reg = 0; reg < 4; ++reg)
        dst[(size_t)reg * 1024] = f2b(acc[i][j][reg] * sc);
    }
  }
}

// ---- GEMM3: out[b][n][f] = relu( Dv^-1[b,n] * sum_e H[n][e]*Yt[f][e] ) ----
// tile 128n x 128f, K=1024, BK=64; A = H f32 reg-staged, B = Yt gload_lds
__global__ __launch_bounds__(256) void k_gemm3(const float* __restrict__ H,
    const uint16_t* __restrict__ Yt, const float* __restrict__ Dv,
    float* __restrict__ out) {
  __shared__ __align__(16) uint16_t As[2][128 * PADK];
  __shared__ __align__(16) uint16_t Bs[2][128 * 64];
  const int n0 = blockIdx.x * 128, f0 = blockIdx.y * 128, b = blockIdx.z;
  const int t = threadIdx.x, lane = t & 63, wave = t >> 6;
  const int l15 = lane & 15, lq = lane >> 4;
  const int rlane = lane >> 3;
  const int srcswz = ((lane & 7) ^ rlane) << 3;
  const int arow = t >> 1, ac0 = (t & 1) * 32;
  const float* Agb = H + ((size_t)b * 2048 + n0 + arow) * 1024 + ac0;
  const uint16_t* Bg = Yt + ((size_t)b * 256 + f0) * 1024;
  float4 R[8];
  auto gloadA = [&](int kt) {
    const float* s = Agb + kt * 64;
    #pragma unroll
    for (int q = 0; q < 8; ++q) R[q] = *(const float4*)(s + q * 4);
  };
  auto writeA = [&](uint16_t* Ad) {
    uint16_t* d = Ad + arow * PADK + ac0;
    const float* f = (const float*)R;
    #pragma unroll
    for (int q = 0; q < 4; ++q) {
      union { uint16_t s[8]; uint4 u; } p;
      #pragma unroll
      for (int j = 0; j < 8; ++j) p.s[j] = f2b(f[q * 8 + j]);
      *(uint4*)(d + q * 8) = p.u;
    }
  };
  auto stageB = [&](uint16_t* Bd, int kt) {
    #pragma unroll
    for (int i = 0; i < 4; ++i) {
      const int rB = wave * 32 + i * 8;
      gload16(Bg + (size_t)(rB + rlane) * 1024 + kt * 64 + srcswz, Bd + rB * 64);
    }
  };
  f32x4 acc[4][4] = {};
  auto compute = [&](const uint16_t* Ad, const uint16_t* Bd) {
    #pragma unroll
    for (int h = 0; h < 2; ++h) {
      bf16x8 af[4], bf[4];
      #pragma unroll
      for (int i = 0; i < 4; ++i)
        af[i] = *(const bf16x8*)(Ad + ((wave >> 1) * 64 + i * 16 + l15) * PADK + h * 32 + lq * 8);
      #pragma unroll
      for (int j = 0; j < 4; ++j) {
        const int r = (wave & 1) * 64 + j * 16 + l15;
        bf[j] = *(const bf16x8*)(Bd + r * 64 + ((((h << 2) | lq) ^ (r & 7)) << 3));
      }
      #pragma unroll
      for (int i = 0; i < 4; ++i)
        #pragma unroll
        for (int j = 0; j < 4; ++j)
          acc[i][j] = mfma16(af[i], bf[j], acc[i][j]);
    }
  };
  gloadA(0); stageB(Bs[0], 0); writeA(As[0]);
  __syncthreads();
  for (int kt = 0; kt < 16; kt += 2) {
    gloadA(kt + 1); stageB(Bs[1], kt + 1);
    compute(As[0], Bs[0]);
    writeA(As[1]);
    __syncthreads();
    if (kt + 2 < 16) { gloadA(kt + 2); stageB(Bs[0], kt + 2); }
    compute(As[1], Bs[1]);
    if (kt + 2 < 16) writeA(As[0]);
    __syncthreads();
  }
  #pragma unroll
  for (int i = 0; i < 4; ++i) {
    const int nr = n0 + (wave >> 1) * 64 + i * 16 + lq * 4;
    #pragma unroll
    for (int reg = 0; reg < 4; ++reg) {
      const int row = nr + reg;
      const float sc = 1.0f / (Dv[b * 2048 + row] + 1e-9f);
      #pragma unroll
      for (int j = 0; j < 4; ++j) {
        const int col = f0 + (wave & 1) * 64 + j * 16 + l15;
        const float v = acc[i][j][reg] * sc;
        out[((size_t)b * 2048 + row) * 256 + col] = v > 0.f ? v : 0.f;
      }
    }
  }
}

extern "C" void kernel_launch(void* const* d_in, const int* in_sizes, int n_in,
                              void* d_out, int out_size, void* d_ws, size_t ws_size,
                              hipStream_t stream) {
  (void)in_sizes; (void)n_in; (void)out_size;
  const float* x = (const float*)d_in[0];   // [8,2048,256]
  const float* H = (const float*)d_in[1];   // [8,2048,1024]
  const float* W = (const float*)d_in[2];   // [256,256]
  float* out = (float*)d_out;               // [8,2048,256]

  // workspace layout (bytes):
  //   Hbt bf16 [8,1024,2048] : 0        .. 33554432
  //   XWt bf16 [8,256,2048]  : 33554432 .. 41943040
  //   Yt  bf16 [8,256,1024]  : 41943040 .. 46137344
  //   Dv  f32  [8,2048]      : 46137344 .. 46202880
  //   De  f32  [8,1024]      : 46202880 .. 46235648
  if (ws_size < 46235648) return;
  char* ws = (char*)d_ws;
  uint16_t* Hbt = (uint16_t*)(ws);
  uint16_t* XWt = (uint16_t*)(ws + 33554432);
  uint16_t* Yt  = (uint16_t*)(ws + 41943040);
  float*    Dv  = (float*)(ws + 46137344);
  float*    De  = (float*)(ws + 46202880);

  hipMemsetAsync(Dv, 0, 98304, stream);  // zero Dv+De (contiguous)
  k_prep_h<<<dim3(32, 16, 8), 256, 0, stream>>>(H, Hbt, Dv, De);
  k_gemm1 <<<dim3(16, 2, 8),  256, 0, stream>>>(x, W, XWt);
  k_gemm2 <<<dim3(8, 4, 8),   256, 0, stream>>>(Hbt, XWt, De, Yt);
  k_gemm3 <<<dim3(16, 2, 8),  256, 0, stream>>>(H, Yt, Dv, out);
}

// Round 3
// 111.123 us; speedup vs baseline: 1.6640x; 1.1750x over previous
//
#include <hip/hip_runtime.h>
#include <stdint.h>

// HypergraphConv: B=8, N=2048, E=1024, Fin=Fout=256, fp32 in/out.
// out = relu( Dv^-1 * H @ (De^-1 * (H^T @ (x@W))) )
// All-k-contiguous layouts:
//   prep : H -> Hbt[b][e][n] bf16 (+ Dv,De sums)   [vector-LDS transpose, no LDS atomics]
//   gemm1: XWt[b][f][n] = bf16((x@W)^T)
//   gemm2: Yt[b][f][e] = bf16(De^-1 * XWt@Hbt^T)   both operands global_load_lds+XOR swz
//   gemm3: out[b][n][f] = relu(Dv^-1 * H@Yt^T)
// 2-phase double-buffered K-loop (stage next || compute current), BK=64.

typedef __bf16 bf16x8 __attribute__((ext_vector_type(8)));
typedef float f32x4 __attribute__((ext_vector_type(4)));

#define PADK 72  // padded row stride (elems) for f32-reg-staged GEMM tiles

__device__ __forceinline__ uint16_t f2b(float f) {
  __bf16 h = (__bf16)f;            // native cvt (RNE); compiler packs to v_cvt_pk_bf16_f32
  return __builtin_bit_cast(uint16_t, h);
}

__device__ __forceinline__ f32x4 mfma16(bf16x8 a, bf16x8 b, f32x4 c) {
  return __builtin_amdgcn_mfma_f32_16x16x32_bf16(a, b, c, 0, 0, 0);
}

// async global->LDS, 16B/lane; LDS dest = uniform base + lane*16
__device__ __forceinline__ void gload16(const void* src, void* dst) {
  __builtin_amdgcn_global_load_lds(
      (const __attribute__((address_space(1))) void*)src,
      (__attribute__((address_space(3))) void*)dst, 16, 0, 0);
}

// ---- prep: Hbt[b][e][n] = bf16(H[b][n][e]); Dv row sums; De col sums ----
// 64n x 64e tile. Thread: 4 consecutive n-rows x 4 e-cols.
__global__ __launch_bounds__(256) void k_prep_h(const float* __restrict__ H,
    uint16_t* __restrict__ Hbt, float* __restrict__ Dv, float* __restrict__ De) {
  __shared__ __align__(16) uint16_t T[64 * 68];  // [e][n], stride 68
  __shared__ float cs[4][64];
  const int n0 = blockIdx.x * 64, e0 = blockIdx.y * 64, b = blockIdx.z;
  const int t = threadIdx.x, lane = t & 63, wave = t >> 6;
  const int r0 = (t >> 4) * 4;   // first of 4 consecutive n-rows
  const int cc = (t & 15) * 4;   // first of 4 e-cols
  float vv[4][4];
  float de0 = 0.f, de1 = 0.f, de2 = 0.f, de3 = 0.f;
  #pragma unroll
  for (int i = 0; i < 4; ++i) {
    float4 q = *(const float4*)(H + ((size_t)b * 2048 + n0 + r0 + i) * 1024 + e0 + cc);
    vv[i][0] = q.x; vv[i][1] = q.y; vv[i][2] = q.z; vv[i][3] = q.w;
    float rs = (q.x + q.y) + (q.z + q.w);
    rs += __shfl_xor(rs, 1); rs += __shfl_xor(rs, 2);
    rs += __shfl_xor(rs, 4); rs += __shfl_xor(rs, 8);
    if ((lane & 15) == 0) atomicAdd(&Dv[b * 2048 + n0 + r0 + i], rs);
    de0 += q.x; de1 += q.y; de2 += q.z; de3 += q.w;
  }
  // transposed LDS write: per e-col j, 4 consecutive n as one b64
  #pragma unroll
  for (int j = 0; j < 4; ++j) {
    union { uint16_t s[4]; uint2 u; } p;
    #pragma unroll
    for (int i = 0; i < 4; ++i) p.s[i] = f2b(vv[i][j]);
    *(uint2*)&T[(cc + j) * 68 + r0] = p.u;
  }
  // De partials: reduce over the wave's 16 rows via xor-16/32, no LDS atomics
  de0 += __shfl_xor(de0, 16); de0 += __shfl_xor(de0, 32);
  de1 += __shfl_xor(de1, 16); de1 += __shfl_xor(de1, 32);
  de2 += __shfl_xor(de2, 16); de2 += __shfl_xor(de2, 32);
  de3 += __shfl_xor(de3, 16); de3 += __shfl_xor(de3, 32);
  if (lane < 16) *(float4*)&cs[wave][cc] = make_float4(de0, de1, de2, de3);
  __syncthreads();
  if (t < 64) {
    float s = (cs[0][t] + cs[1][t]) + (cs[2][t] + cs[3][t]);
    atomicAdd(&De[b * 1024 + e0 + t], s);
  }
  // transposed read + coalesced global store: thread -> row e, 16-n chunk
  const int e = t >> 2, c2 = (t & 3) * 16;
  union { uint16_t s[16]; uint4 q[2]; } o;
  #pragma unroll
  for (int m = 0; m < 4; ++m)
    *(uint2*)&o.s[m * 4] = *(const uint2*)&T[e * 68 + c2 + m * 4];
  uint16_t* dst = Hbt + ((size_t)b * 1024 + e0 + e) * 2048 + n0 + c2;
  *(uint4*)dst = o.q[0];
  *(uint4*)(dst + 8) = o.q[1];
}

// ---- GEMM1: XWt[b][f][n] = bf16( sum_k W[k][f] * x[b][n][k] ) ----
// tile 128f x 128n, K=256, BK=64
__global__ __launch_bounds__(256) void k_gemm1(const float* __restrict__ X,
    const float* __restrict__ W, uint16_t* __restrict__ XWt) {
  __shared__ __align__(16) uint16_t As[2][128 * PADK];
  __shared__ __align__(16) uint16_t Bs[2][128 * PADK];
  const int n0 = blockIdx.x * 128, f0 = blockIdx.y * 128, b = blockIdx.z;
  const int t = threadIdx.x, lane = t & 63, wave = t >> 6;
  const int l15 = lane & 15, lq = lane >> 4;
  const int wr = t >> 2, wc = (t & 3) * 32;
  const int brow = t >> 1, bc0 = (t & 1) * 32;
  const float* Wg = W + (size_t)wr * 256 + f0 + wc;
  const float* Xg = X + ((size_t)b * 2048 + n0 + brow) * 256 + bc0;
  float4 RW[8], RX[8];
  auto gloadA = [&](int kt) {
    const float* s = Wg + (size_t)kt * 64 * 256;
    #pragma unroll
    for (int q = 0; q < 8; ++q) RW[q] = *(const float4*)(s + q * 4);
  };
  auto gloadB = [&](int kt) {
    const float* s = Xg + kt * 64;
    #pragma unroll
    for (int q = 0; q < 8; ++q) RX[q] = *(const float4*)(s + q * 4);
  };
  auto writeA = [&](uint16_t* Ad) {
    const float* f = (const float*)RW;
    #pragma unroll
    for (int j = 0; j < 32; ++j) Ad[(wc + j) * PADK + wr] = f2b(f[j]);
  };
  auto writeB = [&](uint16_t* Bd) {
    uint16_t* d = Bd + brow * PADK + bc0;
    const float* f = (const float*)RX;
    #pragma unroll
    for (int q = 0; q < 4; ++q) {
      union { uint16_t s[8]; uint4 u; } p;
      #pragma unroll
      for (int j = 0; j < 8; ++j) p.s[j] = f2b(f[q * 8 + j]);
      *(uint4*)(d + q * 8) = p.u;
    }
  };
  f32x4 acc[4][4] = {};
  auto compute = [&](const uint16_t* Ad, const uint16_t* Bd) {
    #pragma unroll
    for (int h = 0; h < 2; ++h) {
      bf16x8 af[4], bf[4];
      #pragma unroll
      for (int i = 0; i < 4; ++i)
        af[i] = *(const bf16x8*)(Ad + ((wave >> 1) * 64 + i * 16 + l15) * PADK + h * 32 + lq * 8);
      #pragma unroll
      for (int j = 0; j < 4; ++j)
        bf[j] = *(const bf16x8*)(Bd + ((wave & 1) * 64 + j * 16 + l15) * PADK + h * 32 + lq * 8);
      #pragma unroll
      for (int i = 0; i < 4; ++i)
        #pragma unroll
        for (int j = 0; j < 4; ++j)
          acc[i][j] = mfma16(af[i], bf[j], acc[i][j]);
    }
  };
  gloadA(0); gloadB(0); writeA(As[0]); writeB(Bs[0]);
  __syncthreads();
  for (int kt = 0; kt < 4; kt += 2) {
    gloadA(kt + 1); gloadB(kt + 1);
    compute(As[0], Bs[0]);
    writeA(As[1]); writeB(Bs[1]);
    __syncthreads();
    if (kt + 2 < 4) { gloadA(kt + 2); gloadB(kt + 2); }
    compute(As[1], Bs[1]);
    if (kt + 2 < 4) { writeA(As[0]); writeB(Bs[0]); }
    __syncthreads();
  }
  #pragma unroll
  for (int i = 0; i < 4; ++i) {
    const int fr = f0 + (wave >> 1) * 64 + i * 16 + lq * 4;
    #pragma unroll
    for (int j = 0; j < 4; ++j) {
      const int col = n0 + (wave & 1) * 64 + j * 16 + l15;
      #pragma unroll
      for (int reg = 0; reg < 4; ++reg)
        XWt[((size_t)b * 256 + fr + reg) * 2048 + col] = f2b(acc[i][j][reg]);
    }
  }
}

// ---- GEMM2: Yt[b][f][e] = bf16( De^-1[b,e] * sum_n XWt[f][n]*Hbt[e][n] ) ----
// tile 64f x 128e, K=2048, BK=64; both operands gload_lds + XOR swizzle
__global__ __launch_bounds__(256) void k_gemm2(const uint16_t* __restrict__ Hbt,
    const uint16_t* __restrict__ XWt, const float* __restrict__ De,
    uint16_t* __restrict__ Yt) {
  __shared__ __align__(16) uint16_t As[2][64 * 64];
  __shared__ __align__(16) uint16_t Bs[2][128 * 64];
  const int e0 = blockIdx.x * 128, f0 = blockIdx.y * 64, b = blockIdx.z;
  const int t = threadIdx.x, lane = t & 63, wave = t >> 6;
  const int l15 = lane & 15, lq = lane >> 4;
  const int rlane = lane >> 3;
  const int srcswz = ((lane & 7) ^ rlane) << 3;  // source 16B-block permutation
  const uint16_t* Ag = XWt + ((size_t)b * 256 + f0) * 2048;
  const uint16_t* Bg = Hbt + ((size_t)b * 1024 + e0) * 2048;
  auto stage = [&](uint16_t* Ad, uint16_t* Bd, int kt) {
    const int k0 = kt * 64;
    int rb = wave * 16;
    gload16(Ag + (size_t)(rb + rlane) * 2048 + k0 + srcswz, Ad + rb * 64);
    gload16(Ag + (size_t)(rb + 8 + rlane) * 2048 + k0 + srcswz, Ad + (rb + 8) * 64);
    #pragma unroll
    for (int i = 0; i < 4; ++i) {
      int rB = wave * 32 + i * 8;
      gload16(Bg + (size_t)(rB + rlane) * 2048 + k0 + srcswz, Bd + rB * 64);
    }
  };
  f32x4 acc[2][4] = {};
  auto compute = [&](const uint16_t* Ad, const uint16_t* Bd) {
    #pragma unroll
    for (int h = 0; h < 2; ++h) {
      bf16x8 af[2], bf[4];
      #pragma unroll
      for (int i = 0; i < 2; ++i) {
        const int r = (wave >> 1) * 32 + i * 16 + l15;
        af[i] = *(const bf16x8*)(Ad + r * 64 + ((((h << 2) | lq) ^ (r & 7)) << 3));
      }
      #pragma unroll
      for (int j = 0; j < 4; ++j) {
        const int r = (wave & 1) * 64 + j * 16 + l15;
        bf[j] = *(const bf16x8*)(Bd + r * 64 + ((((h << 2) | lq) ^ (r & 7)) << 3));
      }
      #pragma unroll
      for (int i = 0; i < 2; ++i)
        #pragma unroll
        for (int j = 0; j < 4; ++j)
          acc[i][j] = mfma16(af[i], bf[j], acc[i][j]);
    }
  };
  stage(As[0], Bs[0], 0);
  __syncthreads();
  for (int kt = 0; kt < 32; kt += 2) {
    stage(As[1], Bs[1], kt + 1);
    compute(As[0], Bs[0]);
    __syncthreads();
    if (kt + 2 < 32) stage(As[0], Bs[0], kt + 2);
    compute(As[1], Bs[1]);
    __syncthreads();
  }
  #pragma unroll
  for (int i = 0; i < 2; ++i) {
    const int fr = f0 + (wave >> 1) * 32 + i * 16 + lq * 4;
    #pragma unroll
    for (int j = 0; j < 4; ++j) {
      const int e = e0 + (wave & 1) * 64 + j * 16 + l15;
      const float sc = 1.0f / (De[b * 1024 + e] + 1e-9f);
      uint16_t* dst = Yt + ((size_t)b * 256 + fr) * 1024 + e;
      #pragma unroll
      for (int reg = 0; reg < 4; ++reg)
        dst[(size_t)reg * 1024] = f2b(acc[i][j][reg] * sc);
    }
  }
}

// ---- GEMM3: out[b][n][f] = relu( Dv^-1[b,n] * sum_e H[n][e]*Yt[f][e] ) ----
// tile 128n x 128f, K=1024, BK=64; A = H f32 reg-staged, B = Yt gload_lds
__global__ __launch_bounds__(256) void k_gemm3(const float* __restrict__ H,
    const uint16_t* __restrict__ Yt, const float* __restrict__ Dv,
    float* __restrict__ out) {
  __shared__ __align__(16) uint16_t As[2][128 * PADK];
  __shared__ __align__(16) uint16_t Bs[2][128 * 64];
  const int n0 = blockIdx.x * 128, f0 = blockIdx.y * 128, b = blockIdx.z;
  const int t = threadIdx.x, lane = t & 63, wave = t >> 6;
  const int l15 = lane & 15, lq = lane >> 4;
  const int rlane = lane >> 3;
  const int srcswz = ((lane & 7) ^ rlane) << 3;
  const int arow = t >> 1, ac0 = (t & 1) * 32;
  const float* Agb = H + ((size_t)b * 2048 + n0 + arow) * 1024 + ac0;
  const uint16_t* Bg = Yt + ((size_t)b * 256 + f0) * 1024;
  float4 R[8];
  auto gloadA = [&](int kt) {
    const float* s = Agb + kt * 64;
    #pragma unroll
    for (int q = 0; q < 8; ++q) R[q] = *(const float4*)(s + q * 4);
  };
  auto writeA = [&](uint16_t* Ad) {
    uint16_t* d = Ad + arow * PADK + ac0;
    const float* f = (const float*)R;
    #pragma unroll
    for (int q = 0; q < 4; ++q) {
      union { uint16_t s[8]; uint4 u; } p;
      #pragma unroll
      for (int j = 0; j < 8; ++j) p.s[j] = f2b(f[q * 8 + j]);
      *(uint4*)(d + q * 8) = p.u;
    }
  };
  auto stageB = [&](uint16_t* Bd, int kt) {
    #pragma unroll
    for (int i = 0; i < 4; ++i) {
      const int rB = wave * 32 + i * 8;
      gload16(Bg + (size_t)(rB + rlane) * 1024 + kt * 64 + srcswz, Bd + rB * 64);
    }
  };
  f32x4 acc[4][4] = {};
  auto compute = [&](const uint16_t* Ad, const uint16_t* Bd) {
    #pragma unroll
    for (int h = 0; h < 2; ++h) {
      bf16x8 af[4], bf[4];
      #pragma unroll
      for (int i = 0; i < 4; ++i)
        af[i] = *(const bf16x8*)(Ad + ((wave >> 1) * 64 + i * 16 + l15) * PADK + h * 32 + lq * 8);
      #pragma unroll
      for (int j = 0; j < 4; ++j) {
        const int r = (wave & 1) * 64 + j * 16 + l15;
        bf[j] = *(const bf16x8*)(Bd + r * 64 + ((((h << 2) | lq) ^ (r & 7)) << 3));
      }
      #pragma unroll
      for (int i = 0; i < 4; ++i)
        #pragma unroll
        for (int j = 0; j < 4; ++j)
          acc[i][j] = mfma16(af[i], bf[j], acc[i][j]);
    }
  };
  gloadA(0); stageB(Bs[0], 0); writeA(As[0]);
  __syncthreads();
  for (int kt = 0; kt < 16; kt += 2) {
    gloadA(kt + 1); stageB(Bs[1], kt + 1);
    compute(As[0], Bs[0]);
    writeA(As[1]);
    __syncthreads();
    if (kt + 2 < 16) { gloadA(kt + 2); stageB(Bs[0], kt + 2); }
    compute(As[1], Bs[1]);
    if (kt + 2 < 16) writeA(As[0]);
    __syncthreads();
  }
  #pragma unroll
  for (int i = 0; i < 4; ++i) {
    const int nr = n0 + (wave >> 1) * 64 + i * 16 + lq * 4;
    #pragma unroll
    for (int reg = 0; reg < 4; ++reg) {
      const int row = nr + reg;
      const float sc = 1.0f / (Dv[b * 2048 + row] + 1e-9f);
      #pragma unroll
      for (int j = 0; j < 4; ++j) {
        const int col = f0 + (wave & 1) * 64 + j * 16 + l15;
        const float v = acc[i][j][reg] * sc;
        out[((size_t)b * 2048 + row) * 256 + col] = v > 0.f ? v : 0.f;
      }
    }
  }
}

extern "C" void kernel_launch(void* const* d_in, const int* in_sizes, int n_in,
                              void* d_out, int out_size, void* d_ws, size_t ws_size,
                              hipStream_t stream) {
  (void)in_sizes; (void)n_in; (void)out_size;
  const float* x = (const float*)d_in[0];   // [8,2048,256]
  const float* H = (const float*)d_in[1];   // [8,2048,1024]
  const float* W = (const float*)d_in[2];   // [256,256]
  float* out = (float*)d_out;               // [8,2048,256]

  // workspace layout (bytes):
  //   Hbt bf16 [8,1024,2048] : 0        .. 33554432
  //   XWt bf16 [8,256,2048]  : 33554432 .. 41943040
  //   Yt  bf16 [8,256,1024]  : 41943040 .. 46137344
  //   Dv  f32  [8,2048]      : 46137344 .. 46202880
  //   De  f32  [8,1024]      : 46202880 .. 46235648
  if (ws_size < 46235648) return;
  char* ws = (char*)d_ws;
  uint16_t* Hbt = (uint16_t*)(ws);
  uint16_t* XWt = (uint16_t*)(ws + 33554432);
  uint16_t* Yt  = (uint16_t*)(ws + 41943040);
  float*    Dv  = (float*)(ws + 46137344);
  float*    De  = (float*)(ws + 46202880);

  hipMemsetAsync(Dv, 0, 98304, stream);  // zero Dv+De (contiguous)
  k_prep_h<<<dim3(32, 16, 8), 256, 0, stream>>>(H, Hbt, Dv, De);
  k_gemm1 <<<dim3(16, 2, 8),  256, 0, stream>>>(x, W, XWt);
  k_gemm2 <<<dim3(8, 4, 8),   256, 0, stream>>>(Hbt, XWt, De, Yt);
  k_gemm3 <<<dim3(16, 2, 8),  256, 0, stream>>>(H, Yt, Dv, out);
}

// Round 4
// 103.225 us; speedup vs baseline: 1.7913x; 1.0765x over previous
//
#include <hip/hip_runtime.h>
#include <stdint.h>

// HypergraphConv: B=8, N=2048, E=1024, Fin=Fout=256, fp32 in/out.
// out = relu( Dv^-1 * H @ (De^-1 * (H^T @ (x@W))) )
// All-k-contiguous layouts, fully atomic-free (no memset in graph):
//   prep : H -> Hbt[b][e][n] bf16 + DvPart/DePart partial sums (plain stores)
//   reduce: DvInv = 1/(sum DvPart), DeInv = 1/(sum DePart)
//   gemm1: XWt[b][f][n] = bf16((x@W)^T)
//   gemm2: Yt[b][f][e] = bf16(DeInv * XWt@Hbt^T)   both operands gload_lds+XOR swz
//   gemm3: out[b][n][f] = relu(DvInv * H@Yt^T)
// 2-phase double-buffered K-loop (stage next || compute current), BK=64.

typedef __bf16 bf16x8 __attribute__((ext_vector_type(8)));
typedef float f32x4 __attribute__((ext_vector_type(4)));

#define PADK 72  // padded row stride (elems) for f32-reg-staged GEMM tiles

__device__ __forceinline__ uint16_t f2b(float f) {
  __bf16 h = (__bf16)f;            // native cvt (RNE); compiler packs to v_cvt_pk_bf16_f32
  return __builtin_bit_cast(uint16_t, h);
}

__device__ __forceinline__ f32x4 mfma16(bf16x8 a, bf16x8 b, f32x4 c) {
  return __builtin_amdgcn_mfma_f32_16x16x32_bf16(a, b, c, 0, 0, 0);
}

// async global->LDS, 16B/lane; LDS dest = uniform base + lane*16
__device__ __forceinline__ void gload16(const void* src, void* dst) {
  __builtin_amdgcn_global_load_lds(
      (const __attribute__((address_space(1))) void*)src,
      (__attribute__((address_space(3))) void*)dst, 16, 0, 0);
}

// ---- prep: Hbt[b][e][n] = bf16(H[b][n][e]); Dv/De partial sums (no atomics) ----
// block: 64 n-rows x 256 e-cols (4 sub-tiles of 64e). grid (32, 4, 8).
__global__ __launch_bounds__(256) void k_prep_h(const float* __restrict__ H,
    uint16_t* __restrict__ Hbt, float* __restrict__ DvPart, float* __restrict__ DePart) {
  __shared__ __align__(16) uint16_t T[64 * 68];  // [e][n], stride 68
  __shared__ float cs[4][64];
  const int n0 = blockIdx.x * 64, e0b = blockIdx.y * 256, b = blockIdx.z;
  const int t = threadIdx.x, lane = t & 63, wave = t >> 6;
  const int r0 = (t >> 4) * 4;   // first of 4 consecutive n-rows
  const int cc = (t & 15) * 4;   // first of 4 e-cols
  const int er = t >> 2, c2 = (t & 3) * 16;  // readback: row e, 16-n chunk
  float dv[4] = {0.f, 0.f, 0.f, 0.f};
  for (int et = 0; et < 4; ++et) {
    const int e0 = e0b + et * 64;
    float vv[4][4];
    float de0 = 0.f, de1 = 0.f, de2 = 0.f, de3 = 0.f;
    #pragma unroll
    for (int i = 0; i < 4; ++i) {
      float4 q = *(const float4*)(H + ((size_t)b * 2048 + n0 + r0 + i) * 1024 + e0 + cc);
      vv[i][0] = q.x; vv[i][1] = q.y; vv[i][2] = q.z; vv[i][3] = q.w;
      float rs = (q.x + q.y) + (q.z + q.w);
      rs += __shfl_xor(rs, 1); rs += __shfl_xor(rs, 2);
      rs += __shfl_xor(rs, 4); rs += __shfl_xor(rs, 8);
      dv[i] += rs;
      de0 += q.x; de1 += q.y; de2 += q.z; de3 += q.w;
    }
    // transposed LDS write: per e-col j, 4 consecutive n as one b64
    #pragma unroll
    for (int j = 0; j < 4; ++j) {
      union { uint16_t s[4]; uint2 u; } p;
      #pragma unroll
      for (int i = 0; i < 4; ++i) p.s[i] = f2b(vv[i][j]);
      *(uint2*)&T[(cc + j) * 68 + r0] = p.u;
    }
    // De partials: reduce over the wave's 16 rows via xor-16/32
    de0 += __shfl_xor(de0, 16); de0 += __shfl_xor(de0, 32);
    de1 += __shfl_xor(de1, 16); de1 += __shfl_xor(de1, 32);
    de2 += __shfl_xor(de2, 16); de2 += __shfl_xor(de2, 32);
    de3 += __shfl_xor(de3, 16); de3 += __shfl_xor(de3, 32);
    if (lane < 16) *(float4*)&cs[wave][cc] = make_float4(de0, de1, de2, de3);
    __syncthreads();
    // transposed read + coalesced global store
    union { uint16_t s[16]; uint4 q[2]; } o;
    #pragma unroll
    for (int m = 0; m < 4; ++m)
      *(uint2*)&o.s[m * 4] = *(const uint2*)&T[er * 68 + c2 + m * 4];
    uint16_t* dst = Hbt + ((size_t)b * 1024 + e0 + er) * 2048 + n0 + c2;
    *(uint4*)dst = o.q[0];
    *(uint4*)(dst + 8) = o.q[1];
    if (t < 64) {
      float s = (cs[0][t] + cs[1][t]) + (cs[2][t] + cs[3][t]);
      DePart[((size_t)b * 32 + blockIdx.x) * 1024 + e0 + t] = s;
    }
    __syncthreads();
  }
  if ((lane & 15) == 0) {
    #pragma unroll
    for (int i = 0; i < 4; ++i)
      DvPart[((size_t)b * 2048 + n0 + r0 + i) * 4 + blockIdx.y] = dv[i];
  }
}

// ---- reduce: fold partials, store reciprocals ----
// 24576 outputs: idx<16384 -> DvInv[b*2048+n]; else DeInv[b*1024+e]. grid 96.
__global__ __launch_bounds__(256) void k_reduce_inv(const float* __restrict__ DvPart,
    const float* __restrict__ DePart, float* __restrict__ DvInv,
    float* __restrict__ DeInv) {
  const int idx = blockIdx.x * 256 + threadIdx.x;
  if (idx < 16384) {
    float4 p = *(const float4*)(DvPart + (size_t)idx * 4);
    DvInv[idx] = 1.f / (((p.x + p.y) + (p.z + p.w)) + 1e-9f);
  } else {
    const int i2 = idx - 16384;
    const int b = i2 >> 10, e = i2 & 1023;
    float s = 0.f;
    #pragma unroll
    for (int j = 0; j < 32; ++j) s += DePart[((size_t)b * 32 + j) * 1024 + e];
    DeInv[i2] = 1.f / (s + 1e-9f);
  }
}

// ---- GEMM1: XWt[b][f][n] = bf16( sum_k W[k][f] * x[b][n][k] ) ----
// tile 128f x 128n, K=256, BK=64
__global__ __launch_bounds__(256) void k_gemm1(const float* __restrict__ X,
    const float* __restrict__ W, uint16_t* __restrict__ XWt) {
  __shared__ __align__(16) uint16_t As[2][128 * PADK];
  __shared__ __align__(16) uint16_t Bs[2][128 * PADK];
  const int n0 = blockIdx.x * 128, f0 = blockIdx.y * 128, b = blockIdx.z;
  const int t = threadIdx.x, lane = t & 63, wave = t >> 6;
  const int l15 = lane & 15, lq = lane >> 4;
  const int wr = t >> 2, wc = (t & 3) * 32;
  const int brow = t >> 1, bc0 = (t & 1) * 32;
  const float* Wg = W + (size_t)wr * 256 + f0 + wc;
  const float* Xg = X + ((size_t)b * 2048 + n0 + brow) * 256 + bc0;
  float4 RW[8], RX[8];
  auto gloadA = [&](int kt) {
    const float* s = Wg + (size_t)kt * 64 * 256;
    #pragma unroll
    for (int q = 0; q < 8; ++q) RW[q] = *(const float4*)(s + q * 4);
  };
  auto gloadB = [&](int kt) {
    const float* s = Xg + kt * 64;
    #pragma unroll
    for (int q = 0; q < 8; ++q) RX[q] = *(const float4*)(s + q * 4);
  };
  auto writeA = [&](uint16_t* Ad) {
    const float* f = (const float*)RW;
    #pragma unroll
    for (int j = 0; j < 32; ++j) Ad[(wc + j) * PADK + wr] = f2b(f[j]);
  };
  auto writeB = [&](uint16_t* Bd) {
    uint16_t* d = Bd + brow * PADK + bc0;
    const float* f = (const float*)RX;
    #pragma unroll
    for (int q = 0; q < 4; ++q) {
      union { uint16_t s[8]; uint4 u; } p;
      #pragma unroll
      for (int j = 0; j < 8; ++j) p.s[j] = f2b(f[q * 8 + j]);
      *(uint4*)(d + q * 8) = p.u;
    }
  };
  f32x4 acc[4][4] = {};
  auto compute = [&](const uint16_t* Ad, const uint16_t* Bd) {
    #pragma unroll
    for (int h = 0; h < 2; ++h) {
      bf16x8 af[4], bf[4];
      #pragma unroll
      for (int i = 0; i < 4; ++i)
        af[i] = *(const bf16x8*)(Ad + ((wave >> 1) * 64 + i * 16 + l15) * PADK + h * 32 + lq * 8);
      #pragma unroll
      for (int j = 0; j < 4; ++j)
        bf[j] = *(const bf16x8*)(Bd + ((wave & 1) * 64 + j * 16 + l15) * PADK + h * 32 + lq * 8);
      #pragma unroll
      for (int i = 0; i < 4; ++i)
        #pragma unroll
        for (int j = 0; j < 4; ++j)
          acc[i][j] = mfma16(af[i], bf[j], acc[i][j]);
    }
  };
  gloadA(0); gloadB(0); writeA(As[0]); writeB(Bs[0]);
  __syncthreads();
  for (int kt = 0; kt < 4; kt += 2) {
    gloadA(kt + 1); gloadB(kt + 1);
    compute(As[0], Bs[0]);
    writeA(As[1]); writeB(Bs[1]);
    __syncthreads();
    if (kt + 2 < 4) { gloadA(kt + 2); gloadB(kt + 2); }
    compute(As[1], Bs[1]);
    if (kt + 2 < 4) { writeA(As[0]); writeB(Bs[0]); }
    __syncthreads();
  }
  #pragma unroll
  for (int i = 0; i < 4; ++i) {
    const int fr = f0 + (wave >> 1) * 64 + i * 16 + lq * 4;
    #pragma unroll
    for (int j = 0; j < 4; ++j) {
      const int col = n0 + (wave & 1) * 64 + j * 16 + l15;
      #pragma unroll
      for (int reg = 0; reg < 4; ++reg)
        XWt[((size_t)b * 256 + fr + reg) * 2048 + col] = f2b(acc[i][j][reg]);
    }
  }
}

// ---- GEMM2: Yt[b][f][e] = bf16( DeInv[b,e] * sum_n XWt[f][n]*Hbt[e][n] ) ----
// tile 64f x 128e, K=2048, BK=64; both operands gload_lds + XOR swizzle
__global__ __launch_bounds__(256) void k_gemm2(const uint16_t* __restrict__ Hbt,
    const uint16_t* __restrict__ XWt, const float* __restrict__ DeInv,
    uint16_t* __restrict__ Yt) {
  __shared__ __align__(16) uint16_t As[2][64 * 64];
  __shared__ __align__(16) uint16_t Bs[2][128 * 64];
  const int e0 = blockIdx.x * 128, f0 = blockIdx.y * 64, b = blockIdx.z;
  const int t = threadIdx.x, lane = t & 63, wave = t >> 6;
  const int l15 = lane & 15, lq = lane >> 4;
  const int rlane = lane >> 3;
  const int srcswz = ((lane & 7) ^ rlane) << 3;  // source 16B-block permutation
  const uint16_t* Ag = XWt + ((size_t)b * 256 + f0) * 2048;
  const uint16_t* Bg = Hbt + ((size_t)b * 1024 + e0) * 2048;
  auto stage = [&](uint16_t* Ad, uint16_t* Bd, int kt) {
    const int k0 = kt * 64;
    int rb = wave * 16;
    gload16(Ag + (size_t)(rb + rlane) * 2048 + k0 + srcswz, Ad + rb * 64);
    gload16(Ag + (size_t)(rb + 8 + rlane) * 2048 + k0 + srcswz, Ad + (rb + 8) * 64);
    #pragma unroll
    for (int i = 0; i < 4; ++i) {
      int rB = wave * 32 + i * 8;
      gload16(Bg + (size_t)(rB + rlane) * 2048 + k0 + srcswz, Bd + rB * 64);
    }
  };
  f32x4 acc[2][4] = {};
  auto compute = [&](const uint16_t* Ad, const uint16_t* Bd) {
    #pragma unroll
    for (int h = 0; h < 2; ++h) {
      bf16x8 af[2], bf[4];
      #pragma unroll
      for (int i = 0; i < 2; ++i) {
        const int r = (wave >> 1) * 32 + i * 16 + l15;
        af[i] = *(const bf16x8*)(Ad + r * 64 + ((((h << 2) | lq) ^ (r & 7)) << 3));
      }
      #pragma unroll
      for (int j = 0; j < 4; ++j) {
        const int r = (wave & 1) * 64 + j * 16 + l15;
        bf[j] = *(const bf16x8*)(Bd + r * 64 + ((((h << 2) | lq) ^ (r & 7)) << 3));
      }
      #pragma unroll
      for (int i = 0; i < 2; ++i)
        #pragma unroll
        for (int j = 0; j < 4; ++j)
          acc[i][j] = mfma16(af[i], bf[j], acc[i][j]);
    }
  };
  stage(As[0], Bs[0], 0);
  __syncthreads();
  for (int kt = 0; kt < 32; kt += 2) {
    stage(As[1], Bs[1], kt + 1);
    compute(As[0], Bs[0]);
    __syncthreads();
    if (kt + 2 < 32) stage(As[0], Bs[0], kt + 2);
    compute(As[1], Bs[1]);
    __syncthreads();
  }
  #pragma unroll
  for (int i = 0; i < 2; ++i) {
    const int fr = f0 + (wave >> 1) * 32 + i * 16 + lq * 4;
    #pragma unroll
    for (int j = 0; j < 4; ++j) {
      const int e = e0 + (wave & 1) * 64 + j * 16 + l15;
      const float sc = DeInv[b * 1024 + e];
      uint16_t* dst = Yt + ((size_t)b * 256 + fr) * 1024 + e;
      #pragma unroll
      for (int reg = 0; reg < 4; ++reg)
        dst[(size_t)reg * 1024] = f2b(acc[i][j][reg] * sc);
    }
  }
}

// ---- GEMM3: out[b][n][f] = relu( DvInv[b,n] * sum_e H[n][e]*Yt[f][e] ) ----
// tile 128n x 128f, K=1024, BK=64; A = H f32 reg-staged, B = Yt gload_lds
__global__ __launch_bounds__(256) void k_gemm3(const float* __restrict__ H,
    const uint16_t* __restrict__ Yt, const float* __restrict__ DvInv,
    float* __restrict__ out) {
  __shared__ __align__(16) uint16_t As[2][128 * PADK];
  __shared__ __align__(16) uint16_t Bs[2][128 * 64];
  const int n0 = blockIdx.x * 128, f0 = blockIdx.y * 128, b = blockIdx.z;
  const int t = threadIdx.x, lane = t & 63, wave = t >> 6;
  const int l15 = lane & 15, lq = lane >> 4;
  const int rlane = lane >> 3;
  const int srcswz = ((lane & 7) ^ rlane) << 3;
  const int arow = t >> 1, ac0 = (t & 1) * 32;
  const float* Agb = H + ((size_t)b * 2048 + n0 + arow) * 1024 + ac0;
  const uint16_t* Bg = Yt + ((size_t)b * 256 + f0) * 1024;
  float4 R[8];
  auto gloadA = [&](int kt) {
    const float* s = Agb + kt * 64;
    #pragma unroll
    for (int q = 0; q < 8; ++q) R[q] = *(const float4*)(s + q * 4);
  };
  auto writeA = [&](uint16_t* Ad) {
    uint16_t* d = Ad + arow * PADK + ac0;
    const float* f = (const float*)R;
    #pragma unroll
    for (int q = 0; q < 4; ++q) {
      union { uint16_t s[8]; uint4 u; } p;
      #pragma unroll
      for (int j = 0; j < 8; ++j) p.s[j] = f2b(f[q * 8 + j]);
      *(uint4*)(d + q * 8) = p.u;
    }
  };
  auto stageB = [&](uint16_t* Bd, int kt) {
    #pragma unroll
    for (int i = 0; i < 4; ++i) {
      const int rB = wave * 32 + i * 8;
      gload16(Bg + (size_t)(rB + rlane) * 1024 + kt * 64 + srcswz, Bd + rB * 64);
    }
  };
  f32x4 acc[4][4] = {};
  auto compute = [&](const uint16_t* Ad, const uint16_t* Bd) {
    #pragma unroll
    for (int h = 0; h < 2; ++h) {
      bf16x8 af[4], bf[4];
      #pragma unroll
      for (int i = 0; i < 4; ++i)
        af[i] = *(const bf16x8*)(Ad + ((wave >> 1) * 64 + i * 16 + l15) * PADK + h * 32 + lq * 8);
      #pragma unroll
      for (int j = 0; j < 4; ++j) {
        const int r = (wave & 1) * 64 + j * 16 + l15;
        bf[j] = *(const bf16x8*)(Bd + r * 64 + ((((h << 2) | lq) ^ (r & 7)) << 3));
      }
      #pragma unroll
      for (int i = 0; i < 4; ++i)
        #pragma unroll
        for (int j = 0; j < 4; ++j)
          acc[i][j] = mfma16(af[i], bf[j], acc[i][j]);
    }
  };
  gloadA(0); stageB(Bs[0], 0); writeA(As[0]);
  __syncthreads();
  for (int kt = 0; kt < 16; kt += 2) {
    gloadA(kt + 1); stageB(Bs[1], kt + 1);
    compute(As[0], Bs[0]);
    writeA(As[1]);
    __syncthreads();
    if (kt + 2 < 16) { gloadA(kt + 2); stageB(Bs[0], kt + 2); }
    compute(As[1], Bs[1]);
    if (kt + 2 < 16) writeA(As[0]);
    __syncthreads();
  }
  #pragma unroll
  for (int i = 0; i < 4; ++i) {
    const int nr = n0 + (wave >> 1) * 64 + i * 16 + lq * 4;
    #pragma unroll
    for (int reg = 0; reg < 4; ++reg) {
      const int row = nr + reg;
      const float sc = DvInv[b * 2048 + row];
      #pragma unroll
      for (int j = 0; j < 4; ++j) {
        const int col = f0 + (wave & 1) * 64 + j * 16 + l15;
        const float v = acc[i][j][reg] * sc;
        out[((size_t)b * 2048 + row) * 256 + col] = v > 0.f ? v : 0.f;
      }
    }
  }
}

extern "C" void kernel_launch(void* const* d_in, const int* in_sizes, int n_in,
                              void* d_out, int out_size, void* d_ws, size_t ws_size,
                              hipStream_t stream) {
  (void)in_sizes; (void)n_in; (void)out_size;
  const float* x = (const float*)d_in[0];   // [8,2048,256]
  const float* H = (const float*)d_in[1];   // [8,2048,1024]
  const float* W = (const float*)d_in[2];   // [256,256]
  float* out = (float*)d_out;               // [8,2048,256]

  // workspace layout (bytes):
  //   Hbt    bf16 [8,1024,2048] : 0        .. 33554432
  //   XWt    bf16 [8,256,2048]  : 33554432 .. 41943040
  //   Yt     bf16 [8,256,1024]  : 41943040 .. 46137344
  //   DvInv  f32  [8,2048]      : 46137344 .. 46202880
  //   DeInv  f32  [8,1024]      : 46202880 .. 46235648
  //   DvPart f32  [8,2048,4]    : 46235648 .. 46497792
  //   DePart f32  [8,32,1024]   : 46497792 .. 47546368
  if (ws_size < 47546368) return;
  char* ws = (char*)d_ws;
  uint16_t* Hbt    = (uint16_t*)(ws);
  uint16_t* XWt    = (uint16_t*)(ws + 33554432);
  uint16_t* Yt     = (uint16_t*)(ws + 41943040);
  float*    DvInv  = (float*)(ws + 46137344);
  float*    DeInv  = (float*)(ws + 46202880);
  float*    DvPart = (float*)(ws + 46235648);
  float*    DePart = (float*)(ws + 46497792);

  k_prep_h    <<<dim3(32, 4, 8), 256, 0, stream>>>(H, Hbt, DvPart, DePart);
  k_reduce_inv<<<dim3(96),       256, 0, stream>>>(DvPart, DePart, DvInv, DeInv);
  k_gemm1     <<<dim3(16, 2, 8), 256, 0, stream>>>(x, W, XWt);
  k_gemm2     <<<dim3(8, 4, 8),  256, 0, stream>>>(Hbt, XWt, DeInv, Yt);
  k_gemm3     <<<dim3(16, 2, 8), 256, 0, stream>>>(H, Yt, DvInv, out);
}

// Round 5
// 96.318 us; speedup vs baseline: 1.9198x; 1.0717x over previous
//
#include <hip/hip_runtime.h>
#include <stdint.h>

// HypergraphConv: B=8, N=2048, E=1024, Fin=Fout=256, fp32 in/out.
// out = relu( Dv^-1 * H @ (De^-1 * (H^T @ (x@W))) )
// All-k-contiguous layouts, atomic-free, no memset, no reduce kernel:
//   prep : H -> Hbt[b][e][n] bf16 + Hb[b][n][e] bf16 + DvPart/DePart partials
//   gemm1: XWt[b][f][n] = bf16((x@W)^T)
//   gemm2: Yt[b][f][e] = bf16(DeInv * XWt@Hbt^T)  (DeInv folded from DePart in-block)
//   gemm3: out[b][n][f] = relu(DvInv * Hb@Yt^T)   (DvInv folded from DvPart in-block)
// GEMM K-loop: 2-phase double-buffered (stage next || compute current), BK=64.

typedef __bf16 bf16x8 __attribute__((ext_vector_type(8)));
typedef float f32x4 __attribute__((ext_vector_type(4)));

#define PADK 72  // padded row stride (elems) for f32-reg-staged GEMM tiles

__device__ __forceinline__ uint16_t f2b(float f) {
  __bf16 h = (__bf16)f;            // native cvt (RNE); compiler packs to v_cvt_pk_bf16_f32
  return __builtin_bit_cast(uint16_t, h);
}

__device__ __forceinline__ f32x4 mfma16(bf16x8 a, bf16x8 b, f32x4 c) {
  return __builtin_amdgcn_mfma_f32_16x16x32_bf16(a, b, c, 0, 0, 0);
}

// async global->LDS, 16B/lane; LDS dest = uniform base + lane*16
__device__ __forceinline__ void gload16(const void* src, void* dst) {
  __builtin_amdgcn_global_load_lds(
      (const __attribute__((address_space(1))) void*)src,
      (__attribute__((address_space(3))) void*)dst, 16, 0, 0);
}

// ---- prep: Hbt[e][n], Hb[n][e] bf16; Dv/De partial sums (no atomics) ----
// block: 64 n-rows x 256 e-cols (4 sub-tiles of 64e). grid (32, 4, 8).
__global__ __launch_bounds__(256) void k_prep_h(const float* __restrict__ H,
    uint16_t* __restrict__ Hbt, uint16_t* __restrict__ Hb,
    float* __restrict__ DvPart, float* __restrict__ DePart) {
  __shared__ __align__(16) uint16_t T[64 * 68];  // [e][n], stride 68
  __shared__ float cs[4][64];
  const int n0 = blockIdx.x * 64, e0b = blockIdx.y * 256, b = blockIdx.z;
  const int t = threadIdx.x, lane = t & 63, wave = t >> 6;
  const int r0 = (t >> 4) * 4;   // first of 4 consecutive n-rows
  const int cc = (t & 15) * 4;   // first of 4 e-cols
  const int er = t >> 2, c2 = (t & 3) * 16;  // readback: row e, 16-n chunk
  float dv[4] = {0.f, 0.f, 0.f, 0.f};
  for (int et = 0; et < 4; ++et) {
    const int e0 = e0b + et * 64;
    float vv[4][4];
    float de0 = 0.f, de1 = 0.f, de2 = 0.f, de3 = 0.f;
    #pragma unroll
    for (int i = 0; i < 4; ++i) {
      float4 q = *(const float4*)(H + ((size_t)b * 2048 + n0 + r0 + i) * 1024 + e0 + cc);
      vv[i][0] = q.x; vv[i][1] = q.y; vv[i][2] = q.z; vv[i][3] = q.w;
      float rs = (q.x + q.y) + (q.z + q.w);
      rs += __shfl_xor(rs, 1); rs += __shfl_xor(rs, 2);
      rs += __shfl_xor(rs, 4); rs += __shfl_xor(rs, 8);
      dv[i] += rs;
      de0 += q.x; de1 += q.y; de2 += q.z; de3 += q.w;
    }
    // row-major bf16 copy for gemm3 (coalesced 8B stores)
    #pragma unroll
    for (int i = 0; i < 4; ++i) {
      union { uint16_t s[4]; uint2 u; } p;
      #pragma unroll
      for (int j = 0; j < 4; ++j) p.s[j] = f2b(vv[i][j]);
      *(uint2*)(Hb + ((size_t)b * 2048 + n0 + r0 + i) * 1024 + e0 + cc) = p.u;
    }
    // transposed LDS write: per e-col j, 4 consecutive n as one b64
    #pragma unroll
    for (int j = 0; j < 4; ++j) {
      union { uint16_t s[4]; uint2 u; } p;
      #pragma unroll
      for (int i = 0; i < 4; ++i) p.s[i] = f2b(vv[i][j]);
      *(uint2*)&T[(cc + j) * 68 + r0] = p.u;
    }
    // De partials: reduce over the wave's 16 rows via xor-16/32
    de0 += __shfl_xor(de0, 16); de0 += __shfl_xor(de0, 32);
    de1 += __shfl_xor(de1, 16); de1 += __shfl_xor(de1, 32);
    de2 += __shfl_xor(de2, 16); de2 += __shfl_xor(de2, 32);
    de3 += __shfl_xor(de3, 16); de3 += __shfl_xor(de3, 32);
    if (lane < 16) *(float4*)&cs[wave][cc] = make_float4(de0, de1, de2, de3);
    __syncthreads();
    // transposed read + coalesced global store
    union { uint16_t s[16]; uint4 q[2]; } o;
    #pragma unroll
    for (int m = 0; m < 4; ++m)
      *(uint2*)&o.s[m * 4] = *(const uint2*)&T[er * 68 + c2 + m * 4];
    uint16_t* dst = Hbt + ((size_t)b * 1024 + e0 + er) * 2048 + n0 + c2;
    *(uint4*)dst = o.q[0];
    *(uint4*)(dst + 8) = o.q[1];
    if (t < 64) {
      float s = (cs[0][t] + cs[1][t]) + (cs[2][t] + cs[3][t]);
      DePart[((size_t)b * 1024 + e0 + t) * 32 + blockIdx.x] = s;  // [b][e][32]
    }
    __syncthreads();
  }
  if ((lane & 15) == 0) {
    #pragma unroll
    for (int i = 0; i < 4; ++i)
      DvPart[((size_t)b * 2048 + n0 + r0 + i) * 4 + blockIdx.y] = dv[i];
  }
}

// ---- GEMM1: XWt[b][f][n] = bf16( sum_k W[k][f] * x[b][n][k] ) ----
// tile 128f x 128n, K=256, BK=64
__global__ __launch_bounds__(256) void k_gemm1(const float* __restrict__ X,
    const float* __restrict__ W, uint16_t* __restrict__ XWt) {
  __shared__ __align__(16) uint16_t As[2][128 * PADK];
  __shared__ __align__(16) uint16_t Bs[2][128 * PADK];
  const int n0 = blockIdx.x * 128, f0 = blockIdx.y * 128, b = blockIdx.z;
  const int t = threadIdx.x, lane = t & 63, wave = t >> 6;
  const int l15 = lane & 15, lq = lane >> 4;
  const int wr = t >> 2, wc = (t & 3) * 32;
  const int brow = t >> 1, bc0 = (t & 1) * 32;
  const float* Wg = W + (size_t)wr * 256 + f0 + wc;
  const float* Xg = X + ((size_t)b * 2048 + n0 + brow) * 256 + bc0;
  float4 RW[8], RX[8];
  auto gloadA = [&](int kt) {
    const float* s = Wg + (size_t)kt * 64 * 256;
    #pragma unroll
    for (int q = 0; q < 8; ++q) RW[q] = *(const float4*)(s + q * 4);
  };
  auto gloadB = [&](int kt) {
    const float* s = Xg + kt * 64;
    #pragma unroll
    for (int q = 0; q < 8; ++q) RX[q] = *(const float4*)(s + q * 4);
  };
  auto writeA = [&](uint16_t* Ad) {
    const float* f = (const float*)RW;
    #pragma unroll
    for (int j = 0; j < 32; ++j) Ad[(wc + j) * PADK + wr] = f2b(f[j]);
  };
  auto writeB = [&](uint16_t* Bd) {
    uint16_t* d = Bd + brow * PADK + bc0;
    const float* f = (const float*)RX;
    #pragma unroll
    for (int q = 0; q < 4; ++q) {
      union { uint16_t s[8]; uint4 u; } p;
      #pragma unroll
      for (int j = 0; j < 8; ++j) p.s[j] = f2b(f[q * 8 + j]);
      *(uint4*)(d + q * 8) = p.u;
    }
  };
  f32x4 acc[4][4] = {};
  auto compute = [&](const uint16_t* Ad, const uint16_t* Bd) {
    #pragma unroll
    for (int h = 0; h < 2; ++h) {
      bf16x8 af[4], bf[4];
      #pragma unroll
      for (int i = 0; i < 4; ++i)
        af[i] = *(const bf16x8*)(Ad + ((wave >> 1) * 64 + i * 16 + l15) * PADK + h * 32 + lq * 8);
      #pragma unroll
      for (int j = 0; j < 4; ++j)
        bf[j] = *(const bf16x8*)(Bd + ((wave & 1) * 64 + j * 16 + l15) * PADK + h * 32 + lq * 8);
      #pragma unroll
      for (int i = 0; i < 4; ++i)
        #pragma unroll
        for (int j = 0; j < 4; ++j)
          acc[i][j] = mfma16(af[i], bf[j], acc[i][j]);
    }
  };
  gloadA(0); gloadB(0); writeA(As[0]); writeB(Bs[0]);
  __syncthreads();
  for (int kt = 0; kt < 4; kt += 2) {
    gloadA(kt + 1); gloadB(kt + 1);
    compute(As[0], Bs[0]);
    writeA(As[1]); writeB(Bs[1]);
    __syncthreads();
    if (kt + 2 < 4) { gloadA(kt + 2); gloadB(kt + 2); }
    compute(As[1], Bs[1]);
    if (kt + 2 < 4) { writeA(As[0]); writeB(Bs[0]); }
    __syncthreads();
  }
  #pragma unroll
  for (int i = 0; i < 4; ++i) {
    const int fr = f0 + (wave >> 1) * 64 + i * 16 + lq * 4;
    #pragma unroll
    for (int j = 0; j < 4; ++j) {
      const int col = n0 + (wave & 1) * 64 + j * 16 + l15;
      #pragma unroll
      for (int reg = 0; reg < 4; ++reg)
        XWt[((size_t)b * 256 + fr + reg) * 2048 + col] = f2b(acc[i][j][reg]);
    }
  }
}

// ---- GEMM2: Yt[b][f][e] = bf16( DeInv[b,e] * sum_n XWt[f][n]*Hbt[e][n] ) ----
// tile 64f x 128e, K=2048, BK=64; both operands gload_lds + XOR swizzle
__global__ __launch_bounds__(256) void k_gemm2(const uint16_t* __restrict__ Hbt,
    const uint16_t* __restrict__ XWt, const float* __restrict__ DePart,
    uint16_t* __restrict__ Yt) {
  __shared__ __align__(16) uint16_t As[2][64 * 64];
  __shared__ __align__(16) uint16_t Bs[2][128 * 64];
  __shared__ float sde[128];
  const int e0 = blockIdx.x * 128, f0 = blockIdx.y * 64, b = blockIdx.z;
  const int t = threadIdx.x, lane = t & 63, wave = t >> 6;
  const int l15 = lane & 15, lq = lane >> 4;
  const int rlane = lane >> 3;
  const int srcswz = ((lane & 7) ^ rlane) << 3;  // source 16B-block permutation
  const uint16_t* Ag = XWt + ((size_t)b * 256 + f0) * 2048;
  const uint16_t* Bg = Hbt + ((size_t)b * 1024 + e0) * 2048;
  auto stage = [&](uint16_t* Ad, uint16_t* Bd, int kt) {
    const int k0 = kt * 64;
    int rb = wave * 16;
    gload16(Ag + (size_t)(rb + rlane) * 2048 + k0 + srcswz, Ad + rb * 64);
    gload16(Ag + (size_t)(rb + 8 + rlane) * 2048 + k0 + srcswz, Ad + (rb + 8) * 64);
    #pragma unroll
    for (int i = 0; i < 4; ++i) {
      int rB = wave * 32 + i * 8;
      gload16(Bg + (size_t)(rB + rlane) * 2048 + k0 + srcswz, Bd + rB * 64);
    }
  };
  stage(As[0], Bs[0], 0);
  // fold De partials -> reciprocal, once per block (coalesced float4 reads)
  if (t < 128) {
    const float* p = DePart + ((size_t)b * 1024 + e0 + t) * 32;
    float4 a0 = *(const float4*)(p + 0),  a1 = *(const float4*)(p + 4);
    float4 a2 = *(const float4*)(p + 8),  a3 = *(const float4*)(p + 12);
    float4 a4 = *(const float4*)(p + 16), a5 = *(const float4*)(p + 20);
    float4 a6 = *(const float4*)(p + 24), a7 = *(const float4*)(p + 28);
    float s = (((a0.x + a0.y) + (a0.z + a0.w)) + ((a1.x + a1.y) + (a1.z + a1.w)))
            + (((a2.x + a2.y) + (a2.z + a2.w)) + ((a3.x + a3.y) + (a3.z + a3.w)))
            + ((((a4.x + a4.y) + (a4.z + a4.w)) + ((a5.x + a5.y) + (a5.z + a5.w)))
            + (((a6.x + a6.y) + (a6.z + a6.w)) + ((a7.x + a7.y) + (a7.z + a7.w))));
    sde[t] = 1.f / (s + 1e-9f);
  }
  f32x4 acc[2][4] = {};
  auto compute = [&](const uint16_t* Ad, const uint16_t* Bd) {
    #pragma unroll
    for (int h = 0; h < 2; ++h) {
      bf16x8 af[2], bf[4];
      #pragma unroll
      for (int i = 0; i < 2; ++i) {
        const int r = (wave >> 1) * 32 + i * 16 + l15;
        af[i] = *(const bf16x8*)(Ad + r * 64 + ((((h << 2) | lq) ^ (r & 7)) << 3));
      }
      #pragma unroll
      for (int j = 0; j < 4; ++j) {
        const int r = (wave & 1) * 64 + j * 16 + l15;
        bf[j] = *(const bf16x8*)(Bd + r * 64 + ((((h << 2) | lq) ^ (r & 7)) << 3));
      }
      #pragma unroll
      for (int i = 0; i < 2; ++i)
        #pragma unroll
        for (int j = 0; j < 4; ++j)
          acc[i][j] = mfma16(af[i], bf[j], acc[i][j]);
    }
  };
  __syncthreads();
  for (int kt = 0; kt < 32; kt += 2) {
    stage(As[1], Bs[1], kt + 1);
    compute(As[0], Bs[0]);
    __syncthreads();
    if (kt + 2 < 32) stage(As[0], Bs[0], kt + 2);
    compute(As[1], Bs[1]);
    __syncthreads();
  }
  #pragma unroll
  for (int i = 0; i < 2; ++i) {
    const int fr = f0 + (wave >> 1) * 32 + i * 16 + lq * 4;
    #pragma unroll
    for (int j = 0; j < 4; ++j) {
      const int el = (wave & 1) * 64 + j * 16 + l15;
      const float sc = sde[el];
      uint16_t* dst = Yt + ((size_t)b * 256 + fr) * 1024 + e0 + el;
      #pragma unroll
      for (int reg = 0; reg < 4; ++reg)
        dst[(size_t)reg * 1024] = f2b(acc[i][j][reg] * sc);
    }
  }
}

// ---- GEMM3: out[b][n][f] = relu( DvInv[b,n] * sum_e Hb[n][e]*Yt[f][e] ) ----
// tile 128n x 128f, K=1024, BK=64; BOTH operands bf16 via gload_lds + XOR swz
__global__ __launch_bounds__(256) void k_gemm3(const uint16_t* __restrict__ Hb,
    const uint16_t* __restrict__ Yt, const float* __restrict__ DvPart,
    float* __restrict__ out) {
  __shared__ __align__(16) uint16_t As[2][128 * 64];
  __shared__ __align__(16) uint16_t Bs[2][128 * 64];
  __shared__ float sdv[128];
  const int n0 = blockIdx.x * 128, f0 = blockIdx.y * 128, b = blockIdx.z;
  const int t = threadIdx.x, lane = t & 63, wave = t >> 6;
  const int l15 = lane & 15, lq = lane >> 4;
  const int rlane = lane >> 3;
  const int srcswz = ((lane & 7) ^ rlane) << 3;
  const uint16_t* Ag = Hb + ((size_t)b * 2048 + n0) * 1024;
  const uint16_t* Bg = Yt + ((size_t)b * 256 + f0) * 1024;
  auto stage = [&](uint16_t* Ad, uint16_t* Bd, int kt) {
    const int k0 = kt * 64;
    #pragma unroll
    for (int i = 0; i < 4; ++i) {
      const int r = wave * 32 + i * 8;
      gload16(Ag + (size_t)(r + rlane) * 1024 + k0 + srcswz, Ad + r * 64);
      gload16(Bg + (size_t)(r + rlane) * 1024 + k0 + srcswz, Bd + r * 64);
    }
  };
  stage(As[0], Bs[0], 0);
  if (t < 128) {
    float4 p = *(const float4*)(DvPart + ((size_t)b * 2048 + n0 + t) * 4);
    sdv[t] = 1.f / (((p.x + p.y) + (p.z + p.w)) + 1e-9f);
  }
  f32x4 acc[4][4] = {};
  auto compute = [&](const uint16_t* Ad, const uint16_t* Bd) {
    #pragma unroll
    for (int h = 0; h < 2; ++h) {
      bf16x8 af[4], bf[4];
      #pragma unroll
      for (int i = 0; i < 4; ++i) {
        const int r = (wave >> 1) * 64 + i * 16 + l15;
        af[i] = *(const bf16x8*)(Ad + r * 64 + ((((h << 2) | lq) ^ (r & 7)) << 3));
      }
      #pragma unroll
      for (int j = 0; j < 4; ++j) {
        const int r = (wave & 1) * 64 + j * 16 + l15;
        bf[j] = *(const bf16x8*)(Bd + r * 64 + ((((h << 2) | lq) ^ (r & 7)) << 3));
      }
      #pragma unroll
      for (int i = 0; i < 4; ++i)
        #pragma unroll
        for (int j = 0; j < 4; ++j)
          acc[i][j] = mfma16(af[i], bf[j], acc[i][j]);
    }
  };
  __syncthreads();
  for (int kt = 0; kt < 16; kt += 2) {
    stage(As[1], Bs[1], kt + 1);
    compute(As[0], Bs[0]);
    __syncthreads();
    if (kt + 2 < 16) stage(As[0], Bs[0], kt + 2);
    compute(As[1], Bs[1]);
    __syncthreads();
  }
  #pragma unroll
  for (int i = 0; i < 4; ++i) {
    const int rl = (wave >> 1) * 64 + i * 16 + lq * 4;
    #pragma unroll
    for (int reg = 0; reg < 4; ++reg) {
      const int row = n0 + rl + reg;
      const float sc = sdv[rl + reg];
      #pragma unroll
      for (int j = 0; j < 4; ++j) {
        const int col = f0 + (wave & 1) * 64 + j * 16 + l15;
        const float v = acc[i][j][reg] * sc;
        out[((size_t)b * 2048 + row) * 256 + col] = v > 0.f ? v : 0.f;
      }
    }
  }
}

extern "C" void kernel_launch(void* const* d_in, const int* in_sizes, int n_in,
                              void* d_out, int out_size, void* d_ws, size_t ws_size,
                              hipStream_t stream) {
  (void)in_sizes; (void)n_in; (void)out_size;
  const float* x = (const float*)d_in[0];   // [8,2048,256]
  const float* H = (const float*)d_in[1];   // [8,2048,1024]
  const float* W = (const float*)d_in[2];   // [256,256]
  float* out = (float*)d_out;               // [8,2048,256]

  // workspace layout (bytes):
  //   Hbt    bf16 [8,1024,2048] : 0        .. 33554432
  //   Hb     bf16 [8,2048,1024] : 33554432 .. 67108864
  //   XWt    bf16 [8,256,2048]  : 67108864 .. 75497472
  //   Yt     bf16 [8,256,1024]  : 75497472 .. 79691776
  //   DvPart f32  [8,2048,4]    : 79691776 .. 79953920
  //   DePart f32  [8,1024,32]   : 79953920 .. 81002496
  if (ws_size < 81002496) return;
  char* ws = (char*)d_ws;
  uint16_t* Hbt    = (uint16_t*)(ws);
  uint16_t* Hb     = (uint16_t*)(ws + 33554432);
  uint16_t* XWt    = (uint16_t*)(ws + 67108864);
  uint16_t* Yt     = (uint16_t*)(ws + 75497472);
  float*    DvPart = (float*)(ws + 79691776);
  float*    DePart = (float*)(ws + 79953920);

  k_prep_h<<<dim3(32, 4, 8), 256, 0, stream>>>(H, Hbt, Hb, DvPart, DePart);
  k_gemm1 <<<dim3(16, 2, 8), 256, 0, stream>>>(x, W, XWt);
  k_gemm2 <<<dim3(8, 4, 8),  256, 0, stream>>>(Hbt, XWt, DePart, Yt);
  k_gemm3 <<<dim3(16, 2, 8), 256, 0, stream>>>(Hb, Yt, DvPart, out);
}

// Round 6
// 89.378 us; speedup vs baseline: 2.0688x; 1.0777x over previous
//
#include <hip/hip_runtime.h>
#include <stdint.h>

// HypergraphConv: B=8, N=2048, E=1024, Fin=Fout=256, fp32 in/out.
// out = relu( Dv^-1 * H @ (De^-1 * (H^T @ (x@W))) )
// All-k-contiguous layouts, atomic-free, no memset, no reduce kernel.
// R6: all GEMMs retiled to 512-block grids (2-3 blocks/CU) so co-resident
// blocks hide each other's 2-phase barrier/vmcnt stalls (m114 mechanism).
//   prep_w: W -> Wt[f][k] bf16 (one-time transpose)
//   prep_h: H -> Hbt[b][e][n] + Hb[b][n][e] bf16 + DvPart/DePart partials
//   gemm1: XWt[b][f][n] = bf16((x@W)^T)          tile 128f x 64n
//   gemm2: Yt[b][f][e] = bf16(DeInv * XWt@Hbt^T) tile 64f x 64e
//   gemm3: out[b][n][f] = relu(DvInv * Hb@Yt^T)  tile 64n x 128f

typedef __bf16 bf16x8 __attribute__((ext_vector_type(8)));
typedef float f32x4 __attribute__((ext_vector_type(4)));

#define PADK 72  // padded row stride (elems) for f32-reg-staged tiles

__device__ __forceinline__ uint16_t f2b(float f) {
  __bf16 h = (__bf16)f;
  return __builtin_bit_cast(uint16_t, h);
}

__device__ __forceinline__ f32x4 mfma16(bf16x8 a, bf16x8 b, f32x4 c) {
  return __builtin_amdgcn_mfma_f32_16x16x32_bf16(a, b, c, 0, 0, 0);
}

// async global->LDS, 16B/lane; LDS dest = uniform base + lane*16
__device__ __forceinline__ void gload16(const void* src, void* dst) {
  __builtin_amdgcn_global_load_lds(
      (const __attribute__((address_space(1))) void*)src,
      (__attribute__((address_space(3))) void*)dst, 16, 0, 0);
}

// ---- prep_w: Wt[f][k] = bf16(W[k][f]), 64x64 LDS transpose tiles ----
__global__ __launch_bounds__(256) void k_prep_w(const float* __restrict__ W,
    uint16_t* __restrict__ Wt) {
  __shared__ __align__(16) uint16_t T[64 * 68];
  const int k0 = blockIdx.x * 64, f0 = blockIdx.y * 64;
  const int t = threadIdx.x;
  const int r0 = (t >> 4) * 4, cc = (t & 15) * 4;
  float vv[4][4];
  #pragma unroll
  for (int i = 0; i < 4; ++i) {
    float4 q = *(const float4*)(W + (size_t)(k0 + r0 + i) * 256 + f0 + cc);
    vv[i][0] = q.x; vv[i][1] = q.y; vv[i][2] = q.z; vv[i][3] = q.w;
  }
  #pragma unroll
  for (int j = 0; j < 4; ++j) {
    union { uint16_t s[4]; uint2 u; } p;
    #pragma unroll
    for (int i = 0; i < 4; ++i) p.s[i] = f2b(vv[i][j]);
    *(uint2*)&T[(cc + j) * 68 + r0] = p.u;
  }
  __syncthreads();
  const int er = t >> 2, c2 = (t & 3) * 16;
  union { uint16_t s[16]; uint4 q[2]; } o;
  #pragma unroll
  for (int m = 0; m < 4; ++m)
    *(uint2*)&o.s[m * 4] = *(const uint2*)&T[er * 68 + c2 + m * 4];
  uint16_t* dst = Wt + (size_t)(f0 + er) * 256 + k0 + c2;
  *(uint4*)dst = o.q[0];
  *(uint4*)(dst + 8) = o.q[1];
}

// ---- prep_h: Hbt[e][n], Hb[n][e] bf16; Dv/De partial sums (no atomics) ----
// block: 64 n-rows x 256 e-cols (4 sub-tiles of 64e). grid (32, 4, 8).
__global__ __launch_bounds__(256) void k_prep_h(const float* __restrict__ H,
    uint16_t* __restrict__ Hbt, uint16_t* __restrict__ Hb,
    float* __restrict__ DvPart, float* __restrict__ DePart) {
  __shared__ __align__(16) uint16_t T[64 * 68];
  __shared__ float cs[4][64];
  const int n0 = blockIdx.x * 64, e0b = blockIdx.y * 256, b = blockIdx.z;
  const int t = threadIdx.x, lane = t & 63, wave = t >> 6;
  const int r0 = (t >> 4) * 4;
  const int cc = (t & 15) * 4;
  const int er = t >> 2, c2 = (t & 3) * 16;
  float dv[4] = {0.f, 0.f, 0.f, 0.f};
  for (int et = 0; et < 4; ++et) {
    const int e0 = e0b + et * 64;
    float vv[4][4];
    float de0 = 0.f, de1 = 0.f, de2 = 0.f, de3 = 0.f;
    #pragma unroll
    for (int i = 0; i < 4; ++i) {
      float4 q = *(const float4*)(H + ((size_t)b * 2048 + n0 + r0 + i) * 1024 + e0 + cc);
      vv[i][0] = q.x; vv[i][1] = q.y; vv[i][2] = q.z; vv[i][3] = q.w;
      float rs = (q.x + q.y) + (q.z + q.w);
      rs += __shfl_xor(rs, 1); rs += __shfl_xor(rs, 2);
      rs += __shfl_xor(rs, 4); rs += __shfl_xor(rs, 8);
      dv[i] += rs;
      de0 += q.x; de1 += q.y; de2 += q.z; de3 += q.w;
    }
    #pragma unroll
    for (int i = 0; i < 4; ++i) {
      union { uint16_t s[4]; uint2 u; } p;
      #pragma unroll
      for (int j = 0; j < 4; ++j) p.s[j] = f2b(vv[i][j]);
      *(uint2*)(Hb + ((size_t)b * 2048 + n0 + r0 + i) * 1024 + e0 + cc) = p.u;
    }
    #pragma unroll
    for (int j = 0; j < 4; ++j) {
      union { uint16_t s[4]; uint2 u; } p;
      #pragma unroll
      for (int i = 0; i < 4; ++i) p.s[i] = f2b(vv[i][j]);
      *(uint2*)&T[(cc + j) * 68 + r0] = p.u;
    }
    de0 += __shfl_xor(de0, 16); de0 += __shfl_xor(de0, 32);
    de1 += __shfl_xor(de1, 16); de1 += __shfl_xor(de1, 32);
    de2 += __shfl_xor(de2, 16); de2 += __shfl_xor(de2, 32);
    de3 += __shfl_xor(de3, 16); de3 += __shfl_xor(de3, 32);
    if (lane < 16) *(float4*)&cs[wave][cc] = make_float4(de0, de1, de2, de3);
    __syncthreads();
    union { uint16_t s[16]; uint4 q[2]; } o;
    #pragma unroll
    for (int m = 0; m < 4; ++m)
      *(uint2*)&o.s[m * 4] = *(const uint2*)&T[er * 68 + c2 + m * 4];
    uint16_t* dst = Hbt + ((size_t)b * 1024 + e0 + er) * 2048 + n0 + c2;
    *(uint4*)dst = o.q[0];
    *(uint4*)(dst + 8) = o.q[1];
    if (t < 64) {
      float s = (cs[0][t] + cs[1][t]) + (cs[2][t] + cs[3][t]);
      DePart[((size_t)b * 1024 + e0 + t) * 32 + blockIdx.x] = s;  // [b][e][32]
    }
    __syncthreads();
  }
  if ((lane & 15) == 0) {
    #pragma unroll
    for (int i = 0; i < 4; ++i)
      DvPart[((size_t)b * 2048 + n0 + r0 + i) * 4 + blockIdx.y] = dv[i];
  }
}

// ---- GEMM1: XWt[b][f][n] = bf16( sum_k Wt[f][k] * x[b][n][k] ) ----
// tile 128f x 64n, K=256, BK=64. grid (32, 2, 8).
__global__ __launch_bounds__(256) void k_gemm1(const float* __restrict__ X,
    const uint16_t* __restrict__ Wt, uint16_t* __restrict__ XWt) {
  __shared__ __align__(16) uint16_t As[2][128 * 64];  // Wt, gload_lds + XOR swz
  __shared__ __align__(16) uint16_t Bs[2][64 * PADK]; // x, f32 reg-staged, padded
  const int n0 = blockIdx.x * 64, f0 = blockIdx.y * 128, b = blockIdx.z;
  const int t = threadIdx.x, lane = t & 63, wave = t >> 6;
  const int l15 = lane & 15, lq = lane >> 4;
  const int rlane = lane >> 3;
  const int srcswz = ((lane & 7) ^ rlane) << 3;
  const uint16_t* Ag = Wt + (size_t)f0 * 256;
  const int br = t >> 2, kc = (t & 3) * 16;
  const float* Xg = X + ((size_t)b * 2048 + n0 + br) * 256 + kc;
  float4 RX[4];
  auto stageA = [&](uint16_t* Ad, int kt) {
    const int k0 = kt * 64;
    #pragma unroll
    for (int i = 0; i < 4; ++i) {
      const int r = wave * 32 + i * 8;
      gload16(Ag + (size_t)(r + rlane) * 256 + k0 + srcswz, Ad + r * 64);
    }
  };
  auto gloadB = [&](int kt) {
    const float* s = Xg + kt * 64;
    #pragma unroll
    for (int q = 0; q < 4; ++q) RX[q] = *(const float4*)(s + q * 4);
  };
  auto writeB = [&](uint16_t* Bd) {
    uint16_t* d = Bd + br * PADK + kc;
    const float* f = (const float*)RX;
    #pragma unroll
    for (int q = 0; q < 2; ++q) {
      union { uint16_t s[8]; uint4 u; } p;
      #pragma unroll
      for (int j = 0; j < 8; ++j) p.s[j] = f2b(f[q * 8 + j]);
      *(uint4*)(d + q * 8) = p.u;
    }
  };
  f32x4 acc[4][2] = {};
  auto compute = [&](const uint16_t* Ad, const uint16_t* Bd) {
    #pragma unroll
    for (int h = 0; h < 2; ++h) {
      bf16x8 af[4], bf[2];
      #pragma unroll
      for (int i = 0; i < 4; ++i) {
        const int r = (wave >> 1) * 64 + i * 16 + l15;
        af[i] = *(const bf16x8*)(Ad + r * 64 + ((((h << 2) | lq) ^ (r & 7)) << 3));
      }
      #pragma unroll
      for (int j = 0; j < 2; ++j) {
        const int r = (wave & 1) * 32 + j * 16 + l15;
        bf[j] = *(const bf16x8*)(Bd + r * PADK + h * 32 + lq * 8);
      }
      #pragma unroll
      for (int i = 0; i < 4; ++i)
        #pragma unroll
        for (int j = 0; j < 2; ++j)
          acc[i][j] = mfma16(af[i], bf[j], acc[i][j]);
    }
  };
  stageA(As[0], 0); gloadB(0); writeB(Bs[0]);
  __syncthreads();
  for (int kt = 0; kt < 4; kt += 2) {
    stageA(As[1], kt + 1); gloadB(kt + 1);
    compute(As[0], Bs[0]);
    writeB(Bs[1]);
    __syncthreads();
    if (kt + 2 < 4) { stageA(As[0], kt + 2); gloadB(kt + 2); }
    compute(As[1], Bs[1]);
    if (kt + 2 < 4) writeB(Bs[0]);
    __syncthreads();
  }
  #pragma unroll
  for (int i = 0; i < 4; ++i) {
    const int fr = f0 + (wave >> 1) * 64 + i * 16 + lq * 4;
    #pragma unroll
    for (int j = 0; j < 2; ++j) {
      const int col = n0 + (wave & 1) * 32 + j * 16 + l15;
      #pragma unroll
      for (int reg = 0; reg < 4; ++reg)
        XWt[((size_t)b * 256 + fr + reg) * 2048 + col] = f2b(acc[i][j][reg]);
    }
  }
}

// ---- GEMM2: Yt[b][f][e] = bf16( DeInv[b,e] * sum_n XWt[f][n]*Hbt[e][n] ) ----
// tile 64f x 64e, K=2048, BK=64. grid (16, 4, 8). both operands gload_lds.
__global__ __launch_bounds__(256) void k_gemm2(const uint16_t* __restrict__ Hbt,
    const uint16_t* __restrict__ XWt, const float* __restrict__ DePart,
    uint16_t* __restrict__ Yt) {
  __shared__ __align__(16) uint16_t As[2][64 * 64];
  __shared__ __align__(16) uint16_t Bs[2][64 * 64];
  __shared__ float sde[64];
  const int e0 = blockIdx.x * 64, f0 = blockIdx.y * 64, b = blockIdx.z;
  const int t = threadIdx.x, lane = t & 63, wave = t >> 6;
  const int l15 = lane & 15, lq = lane >> 4;
  const int rlane = lane >> 3;
  const int srcswz = ((lane & 7) ^ rlane) << 3;
  const uint16_t* Ag = XWt + ((size_t)b * 256 + f0) * 2048;
  const uint16_t* Bg = Hbt + ((size_t)b * 1024 + e0) * 2048;
  auto stage = [&](uint16_t* Ad, uint16_t* Bd, int kt) {
    const int k0 = kt * 64;
    #pragma unroll
    for (int i = 0; i < 2; ++i) {
      const int r = wave * 16 + i * 8;
      gload16(Ag + (size_t)(r + rlane) * 2048 + k0 + srcswz, Ad + r * 64);
      gload16(Bg + (size_t)(r + rlane) * 2048 + k0 + srcswz, Bd + r * 64);
    }
  };
  stage(As[0], Bs[0], 0);
  if (t < 64) {
    const float* p = DePart + ((size_t)b * 1024 + e0 + t) * 32;
    float4 a0 = *(const float4*)(p + 0),  a1 = *(const float4*)(p + 4);
    float4 a2 = *(const float4*)(p + 8),  a3 = *(const float4*)(p + 12);
    float4 a4 = *(const float4*)(p + 16), a5 = *(const float4*)(p + 20);
    float4 a6 = *(const float4*)(p + 24), a7 = *(const float4*)(p + 28);
    float s = (((a0.x + a0.y) + (a0.z + a0.w)) + ((a1.x + a1.y) + (a1.z + a1.w)))
            + (((a2.x + a2.y) + (a2.z + a2.w)) + ((a3.x + a3.y) + (a3.z + a3.w)))
            + ((((a4.x + a4.y) + (a4.z + a4.w)) + ((a5.x + a5.y) + (a5.z + a5.w)))
            + (((a6.x + a6.y) + (a6.z + a6.w)) + ((a7.x + a7.y) + (a7.z + a7.w))));
    sde[t] = 1.f / (s + 1e-9f);
  }
  f32x4 acc[2][2] = {};
  auto compute = [&](const uint16_t* Ad, const uint16_t* Bd) {
    #pragma unroll
    for (int h = 0; h < 2; ++h) {
      bf16x8 af[2], bf[2];
      #pragma unroll
      for (int i = 0; i < 2; ++i) {
        const int r = (wave >> 1) * 32 + i * 16 + l15;
        af[i] = *(const bf16x8*)(Ad + r * 64 + ((((h << 2) | lq) ^ (r & 7)) << 3));
      }
      #pragma unroll
      for (int j = 0; j < 2; ++j) {
        const int r = (wave & 1) * 32 + j * 16 + l15;
        bf[j] = *(const bf16x8*)(Bd + r * 64 + ((((h << 2) | lq) ^ (r & 7)) << 3));
      }
      #pragma unroll
      for (int i = 0; i < 2; ++i)
        #pragma unroll
        for (int j = 0; j < 2; ++j)
          acc[i][j] = mfma16(af[i], bf[j], acc[i][j]);
    }
  };
  __syncthreads();
  for (int kt = 0; kt < 32; kt += 2) {
    stage(As[1], Bs[1], kt + 1);
    compute(As[0], Bs[0]);
    __syncthreads();
    if (kt + 2 < 32) stage(As[0], Bs[0], kt + 2);
    compute(As[1], Bs[1]);
    __syncthreads();
  }
  #pragma unroll
  for (int i = 0; i < 2; ++i) {
    const int fr = f0 + (wave >> 1) * 32 + i * 16 + lq * 4;
    #pragma unroll
    for (int j = 0; j < 2; ++j) {
      const int el = (wave & 1) * 32 + j * 16 + l15;
      const float sc = sde[el];
      uint16_t* dst = Yt + ((size_t)b * 256 + fr) * 1024 + e0 + el;
      #pragma unroll
      for (int reg = 0; reg < 4; ++reg)
        dst[(size_t)reg * 1024] = f2b(acc[i][j][reg] * sc);
    }
  }
}

// ---- GEMM3: out[b][n][f] = relu( DvInv[b,n] * sum_e Hb[n][e]*Yt[f][e] ) ----
// tile 64n x 128f, K=1024, BK=64. grid (32, 2, 8). both operands gload_lds.
__global__ __launch_bounds__(256) void k_gemm3(const uint16_t* __restrict__ Hb,
    const uint16_t* __restrict__ Yt, const float* __restrict__ DvPart,
    float* __restrict__ out) {
  __shared__ __align__(16) uint16_t As[2][64 * 64];
  __shared__ __align__(16) uint16_t Bs[2][128 * 64];
  __shared__ float sdv[64];
  const int n0 = blockIdx.x * 64, f0 = blockIdx.y * 128, b = blockIdx.z;
  const int t = threadIdx.x, lane = t & 63, wave = t >> 6;
  const int l15 = lane & 15, lq = lane >> 4;
  const int rlane = lane >> 3;
  const int srcswz = ((lane & 7) ^ rlane) << 3;
  const uint16_t* Ag = Hb + ((size_t)b * 2048 + n0) * 1024;
  const uint16_t* Bg = Yt + ((size_t)b * 256 + f0) * 1024;
  auto stage = [&](uint16_t* Ad, uint16_t* Bd, int kt) {
    const int k0 = kt * 64;
    #pragma unroll
    for (int i = 0; i < 2; ++i) {
      const int r = wave * 16 + i * 8;
      gload16(Ag + (size_t)(r + rlane) * 1024 + k0 + srcswz, Ad + r * 64);
    }
    #pragma unroll
    for (int i = 0; i < 4; ++i) {
      const int r = wave * 32 + i * 8;
      gload16(Bg + (size_t)(r + rlane) * 1024 + k0 + srcswz, Bd + r * 64);
    }
  };
  stage(As[0], Bs[0], 0);
  if (t < 64) {
    float4 p = *(const float4*)(DvPart + ((size_t)b * 2048 + n0 + t) * 4);
    sdv[t] = 1.f / (((p.x + p.y) + (p.z + p.w)) + 1e-9f);
  }
  f32x4 acc[2][4] = {};
  auto compute = [&](const uint16_t* Ad, const uint16_t* Bd) {
    #pragma unroll
    for (int h = 0; h < 2; ++h) {
      bf16x8 af[2], bf[4];
      #pragma unroll
      for (int i = 0; i < 2; ++i) {
        const int r = (wave >> 1) * 32 + i * 16 + l15;
        af[i] = *(const bf16x8*)(Ad + r * 64 + ((((h << 2) | lq) ^ (r & 7)) << 3));
      }
      #pragma unroll
      for (int j = 0; j < 4; ++j) {
        const int r = (wave & 1) * 64 + j * 16 + l15;
        bf[j] = *(const bf16x8*)(Bd + r * 64 + ((((h << 2) | lq) ^ (r & 7)) << 3));
      }
      #pragma unroll
      for (int i = 0; i < 2; ++i)
        #pragma unroll
        for (int j = 0; j < 4; ++j)
          acc[i][j] = mfma16(af[i], bf[j], acc[i][j]);
    }
  };
  __syncthreads();
  for (int kt = 0; kt < 16; kt += 2) {
    stage(As[1], Bs[1], kt + 1);
    compute(As[0], Bs[0]);
    __syncthreads();
    if (kt + 2 < 16) stage(As[0], Bs[0], kt + 2);
    compute(As[1], Bs[1]);
    __syncthreads();
  }
  #pragma unroll
  for (int i = 0; i < 2; ++i) {
    const int nl = (wave >> 1) * 32 + i * 16 + lq * 4;
    #pragma unroll
    for (int reg = 0; reg < 4; ++reg) {
      const int row = n0 + nl + reg;
      const float sc = sdv[nl + reg];
      #pragma unroll
      for (int j = 0; j < 4; ++j) {
        const int col = f0 + (wave & 1) * 64 + j * 16 + l15;
        const float v = acc[i][j][reg] * sc;
        out[((size_t)b * 2048 + row) * 256 + col] = v > 0.f ? v : 0.f;
      }
    }
  }
}

extern "C" void kernel_launch(void* const* d_in, const int* in_sizes, int n_in,
                              void* d_out, int out_size, void* d_ws, size_t ws_size,
                              hipStream_t stream) {
  (void)in_sizes; (void)n_in; (void)out_size;
  const float* x = (const float*)d_in[0];   // [8,2048,256]
  const float* H = (const float*)d_in[1];   // [8,2048,1024]
  const float* W = (const float*)d_in[2];   // [256,256]
  float* out = (float*)d_out;               // [8,2048,256]

  // workspace layout (bytes):
  //   Hbt    bf16 [8,1024,2048] : 0        .. 33554432
  //   Hb     bf16 [8,2048,1024] : 33554432 .. 67108864
  //   XWt    bf16 [8,256,2048]  : 67108864 .. 75497472
  //   Yt     bf16 [8,256,1024]  : 75497472 .. 79691776
  //   DvPart f32  [8,2048,4]    : 79691776 .. 79953920
  //   DePart f32  [8,1024,32]   : 79953920 .. 81002496
  //   Wt     bf16 [256,256]     : 81002496 .. 81133568
  if (ws_size < 81133568) return;
  char* ws = (char*)d_ws;
  uint16_t* Hbt    = (uint16_t*)(ws);
  uint16_t* Hb     = (uint16_t*)(ws + 33554432);
  uint16_t* XWt    = (uint16_t*)(ws + 67108864);
  uint16_t* Yt     = (uint16_t*)(ws + 75497472);
  float*    DvPart = (float*)(ws + 79691776);
  float*    DePart = (float*)(ws + 79953920);
  uint16_t* Wt     = (uint16_t*)(ws + 81002496);

  k_prep_w<<<dim3(4, 4),     256, 0, stream>>>(W, Wt);
  k_prep_h<<<dim3(32, 4, 8), 256, 0, stream>>>(H, Hbt, Hb, DvPart, DePart);
  k_gemm1 <<<dim3(32, 2, 8), 256, 0, stream>>>(x, Wt, XWt);
  k_gemm2 <<<dim3(16, 4, 8), 256, 0, stream>>>(Hbt, XWt, DePart, Yt);
  k_gemm3 <<<dim3(32, 2, 8), 256, 0, stream>>>(Hb, Yt, DvPart, out);
}

// Round 7
// 79.690 us; speedup vs baseline: 2.3203x; 1.1216x over previous
//
#include <hip/hip_runtime.h>
#include <stdint.h>

// HypergraphConv: B=8, N=2048, E=1024, Fin=Fout=256, fp32 in/out.
// out = relu( Dv^-1 * H @ (De^-1 * (H^T @ (x@W))) )
// R7: gemm2/gemm3 -> 3-buffer depth-2 pipeline, counted vmcnt(4), raw s_barrier
// (T3/T4-minimum). One barrier per K-step; loads for tile t+1 stay in flight
// across the barrier. prep_w/prep_h/gemm1 unchanged from R6.

typedef __bf16 bf16x8 __attribute__((ext_vector_type(8)));
typedef float f32x4 __attribute__((ext_vector_type(4)));

#define PADK 72  // padded row stride (elems) for f32-reg-staged tiles

__device__ __forceinline__ uint16_t f2b(float f) {
  __bf16 h = (__bf16)f;
  return __builtin_bit_cast(uint16_t, h);
}

__device__ __forceinline__ f32x4 mfma16(bf16x8 a, bf16x8 b, f32x4 c) {
  return __builtin_amdgcn_mfma_f32_16x16x32_bf16(a, b, c, 0, 0, 0);
}

// async global->LDS, 16B/lane; LDS dest = uniform base + lane*16
__device__ __forceinline__ void gload16(const void* src, void* dst) {
  __builtin_amdgcn_global_load_lds(
      (const __attribute__((address_space(1))) void*)src,
      (__attribute__((address_space(3))) void*)dst, 16, 0, 0);
}

#define PIPE_WAIT4() do { \
    asm volatile("s_waitcnt vmcnt(4)" ::: "memory"); \
    __builtin_amdgcn_s_barrier(); \
    __builtin_amdgcn_sched_barrier(0); \
  } while (0)
#define PIPE_WAIT0() do { \
    asm volatile("s_waitcnt vmcnt(0)" ::: "memory"); \
    __builtin_amdgcn_s_barrier(); \
    __builtin_amdgcn_sched_barrier(0); \
  } while (0)

// ---- prep_w: Wt[f][k] = bf16(W[k][f]), 64x64 LDS transpose tiles ----
__global__ __launch_bounds__(256) void k_prep_w(const float* __restrict__ W,
    uint16_t* __restrict__ Wt) {
  __shared__ __align__(16) uint16_t T[64 * 68];
  const int k0 = blockIdx.x * 64, f0 = blockIdx.y * 64;
  const int t = threadIdx.x;
  const int r0 = (t >> 4) * 4, cc = (t & 15) * 4;
  float vv[4][4];
  #pragma unroll
  for (int i = 0; i < 4; ++i) {
    float4 q = *(const float4*)(W + (size_t)(k0 + r0 + i) * 256 + f0 + cc);
    vv[i][0] = q.x; vv[i][1] = q.y; vv[i][2] = q.z; vv[i][3] = q.w;
  }
  #pragma unroll
  for (int j = 0; j < 4; ++j) {
    union { uint16_t s[4]; uint2 u; } p;
    #pragma unroll
    for (int i = 0; i < 4; ++i) p.s[i] = f2b(vv[i][j]);
    *(uint2*)&T[(cc + j) * 68 + r0] = p.u;
  }
  __syncthreads();
  const int er = t >> 2, c2 = (t & 3) * 16;
  union { uint16_t s[16]; uint4 q[2]; } o;
  #pragma unroll
  for (int m = 0; m < 4; ++m)
    *(uint2*)&o.s[m * 4] = *(const uint2*)&T[er * 68 + c2 + m * 4];
  uint16_t* dst = Wt + (size_t)(f0 + er) * 256 + k0 + c2;
  *(uint4*)dst = o.q[0];
  *(uint4*)(dst + 8) = o.q[1];
}

// ---- prep_h: Hbt[e][n], Hb[n][e] bf16; Dv/De partial sums (no atomics) ----
// block: 64 n-rows x 256 e-cols (4 sub-tiles of 64e). grid (32, 4, 8).
__global__ __launch_bounds__(256) void k_prep_h(const float* __restrict__ H,
    uint16_t* __restrict__ Hbt, uint16_t* __restrict__ Hb,
    float* __restrict__ DvPart, float* __restrict__ DePart) {
  __shared__ __align__(16) uint16_t T[64 * 68];
  __shared__ float cs[4][64];
  const int n0 = blockIdx.x * 64, e0b = blockIdx.y * 256, b = blockIdx.z;
  const int t = threadIdx.x, lane = t & 63, wave = t >> 6;
  const int r0 = (t >> 4) * 4;
  const int cc = (t & 15) * 4;
  const int er = t >> 2, c2 = (t & 3) * 16;
  float dv[4] = {0.f, 0.f, 0.f, 0.f};
  for (int et = 0; et < 4; ++et) {
    const int e0 = e0b + et * 64;
    float vv[4][4];
    float de0 = 0.f, de1 = 0.f, de2 = 0.f, de3 = 0.f;
    #pragma unroll
    for (int i = 0; i < 4; ++i) {
      float4 q = *(const float4*)(H + ((size_t)b * 2048 + n0 + r0 + i) * 1024 + e0 + cc);
      vv[i][0] = q.x; vv[i][1] = q.y; vv[i][2] = q.z; vv[i][3] = q.w;
      float rs = (q.x + q.y) + (q.z + q.w);
      rs += __shfl_xor(rs, 1); rs += __shfl_xor(rs, 2);
      rs += __shfl_xor(rs, 4); rs += __shfl_xor(rs, 8);
      dv[i] += rs;
      de0 += q.x; de1 += q.y; de2 += q.z; de3 += q.w;
    }
    #pragma unroll
    for (int i = 0; i < 4; ++i) {
      union { uint16_t s[4]; uint2 u; } p;
      #pragma unroll
      for (int j = 0; j < 4; ++j) p.s[j] = f2b(vv[i][j]);
      *(uint2*)(Hb + ((size_t)b * 2048 + n0 + r0 + i) * 1024 + e0 + cc) = p.u;
    }
    #pragma unroll
    for (int j = 0; j < 4; ++j) {
      union { uint16_t s[4]; uint2 u; } p;
      #pragma unroll
      for (int i = 0; i < 4; ++i) p.s[i] = f2b(vv[i][j]);
      *(uint2*)&T[(cc + j) * 68 + r0] = p.u;
    }
    de0 += __shfl_xor(de0, 16); de0 += __shfl_xor(de0, 32);
    de1 += __shfl_xor(de1, 16); de1 += __shfl_xor(de1, 32);
    de2 += __shfl_xor(de2, 16); de2 += __shfl_xor(de2, 32);
    de3 += __shfl_xor(de3, 16); de3 += __shfl_xor(de3, 32);
    if (lane < 16) *(float4*)&cs[wave][cc] = make_float4(de0, de1, de2, de3);
    __syncthreads();
    union { uint16_t s[16]; uint4 q[2]; } o;
    #pragma unroll
    for (int m = 0; m < 4; ++m)
      *(uint2*)&o.s[m * 4] = *(const uint2*)&T[er * 68 + c2 + m * 4];
    uint16_t* dst = Hbt + ((size_t)b * 1024 + e0 + er) * 2048 + n0 + c2;
    *(uint4*)dst = o.q[0];
    *(uint4*)(dst + 8) = o.q[1];
    if (t < 64) {
      float s = (cs[0][t] + cs[1][t]) + (cs[2][t] + cs[3][t]);
      DePart[((size_t)b * 1024 + e0 + t) * 32 + blockIdx.x] = s;  // [b][e][32]
    }
    __syncthreads();
  }
  if ((lane & 15) == 0) {
    #pragma unroll
    for (int i = 0; i < 4; ++i)
      DvPart[((size_t)b * 2048 + n0 + r0 + i) * 4 + blockIdx.y] = dv[i];
  }
}

// ---- GEMM1: XWt[b][f][n] = bf16( sum_k Wt[f][k] * x[b][n][k] ) ----
// tile 128f x 64n, K=256, BK=64. grid (32, 2, 8).
__global__ __launch_bounds__(256) void k_gemm1(const float* __restrict__ X,
    const uint16_t* __restrict__ Wt, uint16_t* __restrict__ XWt) {
  __shared__ __align__(16) uint16_t As[2][128 * 64];  // Wt, gload_lds + XOR swz
  __shared__ __align__(16) uint16_t Bs[2][64 * PADK]; // x, f32 reg-staged, padded
  const int n0 = blockIdx.x * 64, f0 = blockIdx.y * 128, b = blockIdx.z;
  const int t = threadIdx.x, lane = t & 63, wave = t >> 6;
  const int l15 = lane & 15, lq = lane >> 4;
  const int rlane = lane >> 3;
  const int srcswz = ((lane & 7) ^ rlane) << 3;
  const uint16_t* Ag = Wt + (size_t)f0 * 256;
  const int br = t >> 2, kc = (t & 3) * 16;
  const float* Xg = X + ((size_t)b * 2048 + n0 + br) * 256 + kc;
  float4 RX[4];
  auto stageA = [&](uint16_t* Ad, int kt) {
    const int k0 = kt * 64;
    #pragma unroll
    for (int i = 0; i < 4; ++i) {
      const int r = wave * 32 + i * 8;
      gload16(Ag + (size_t)(r + rlane) * 256 + k0 + srcswz, Ad + r * 64);
    }
  };
  auto gloadB = [&](int kt) {
    const float* s = Xg + kt * 64;
    #pragma unroll
    for (int q = 0; q < 4; ++q) RX[q] = *(const float4*)(s + q * 4);
  };
  auto writeB = [&](uint16_t* Bd) {
    uint16_t* d = Bd + br * PADK + kc;
    const float* f = (const float*)RX;
    #pragma unroll
    for (int q = 0; q < 2; ++q) {
      union { uint16_t s[8]; uint4 u; } p;
      #pragma unroll
      for (int j = 0; j < 8; ++j) p.s[j] = f2b(f[q * 8 + j]);
      *(uint4*)(d + q * 8) = p.u;
    }
  };
  f32x4 acc[4][2] = {};
  auto compute = [&](const uint16_t* Ad, const uint16_t* Bd) {
    #pragma unroll
    for (int h = 0; h < 2; ++h) {
      bf16x8 af[4], bf[2];
      #pragma unroll
      for (int i = 0; i < 4; ++i) {
        const int r = (wave >> 1) * 64 + i * 16 + l15;
        af[i] = *(const bf16x8*)(Ad + r * 64 + ((((h << 2) | lq) ^ (r & 7)) << 3));
      }
      #pragma unroll
      for (int j = 0; j < 2; ++j) {
        const int r = (wave & 1) * 32 + j * 16 + l15;
        bf[j] = *(const bf16x8*)(Bd + r * PADK + h * 32 + lq * 8);
      }
      #pragma unroll
      for (int i = 0; i < 4; ++i)
        #pragma unroll
        for (int j = 0; j < 2; ++j)
          acc[i][j] = mfma16(af[i], bf[j], acc[i][j]);
    }
  };
  stageA(As[0], 0); gloadB(0); writeB(Bs[0]);
  __syncthreads();
  for (int kt = 0; kt < 4; kt += 2) {
    stageA(As[1], kt + 1); gloadB(kt + 1);
    compute(As[0], Bs[0]);
    writeB(Bs[1]);
    __syncthreads();
    if (kt + 2 < 4) { stageA(As[0], kt + 2); gloadB(kt + 2); }
    compute(As[1], Bs[1]);
    if (kt + 2 < 4) writeB(Bs[0]);
    __syncthreads();
  }
  #pragma unroll
  for (int i = 0; i < 4; ++i) {
    const int fr = f0 + (wave >> 1) * 64 + i * 16 + lq * 4;
    #pragma unroll
    for (int j = 0; j < 2; ++j) {
      const int col = n0 + (wave & 1) * 32 + j * 16 + l15;
      #pragma unroll
      for (int reg = 0; reg < 4; ++reg)
        XWt[((size_t)b * 256 + fr + reg) * 2048 + col] = f2b(acc[i][j][reg]);
    }
  }
}

// ---- GEMM2: Yt[b][f][e] = bf16( DeInv[b,e] * sum_n XWt[f][n]*Hbt[e][n] ) ----
// tile 64f x 64e, K=2048 (NT=32 steps of 64). grid (16, 4, 8).
// 3-buffer depth-2 pipeline, vmcnt(4), one raw barrier per step.
__global__ __launch_bounds__(256) void k_gemm2(const uint16_t* __restrict__ Hbt,
    const uint16_t* __restrict__ XWt, const float* __restrict__ DePart,
    uint16_t* __restrict__ Yt) {
  __shared__ __align__(16) uint16_t As[3][64 * 64];
  __shared__ __align__(16) uint16_t Bs[3][64 * 64];
  __shared__ float sde[64];
  const int e0 = blockIdx.x * 64, f0 = blockIdx.y * 64, b = blockIdx.z;
  const int t = threadIdx.x, lane = t & 63, wave = t >> 6;
  const int l15 = lane & 15, lq = lane >> 4;
  const int rlane = lane >> 3;
  const int srcswz = ((lane & 7) ^ rlane) << 3;
  const uint16_t* Ag = XWt + ((size_t)b * 256 + f0) * 2048;
  const uint16_t* Bg = Hbt + ((size_t)b * 1024 + e0) * 2048;
  auto stage = [&](uint16_t* Ad, uint16_t* Bd, int kt) {  // 4 VMEM instrs/wave
    const int k0 = kt * 64;
    #pragma unroll
    for (int i = 0; i < 2; ++i) {
      const int r = wave * 16 + i * 8;
      gload16(Ag + (size_t)(r + rlane) * 2048 + k0 + srcswz, Ad + r * 64);
      gload16(Bg + (size_t)(r + rlane) * 2048 + k0 + srcswz, Bd + r * 64);
    }
  };
  f32x4 acc[2][2] = {};
  auto compute = [&](const uint16_t* Ad, const uint16_t* Bd) {
    #pragma unroll
    for (int h = 0; h < 2; ++h) {
      bf16x8 af[2], bf[2];
      #pragma unroll
      for (int i = 0; i < 2; ++i) {
        const int r = (wave >> 1) * 32 + i * 16 + l15;
        af[i] = *(const bf16x8*)(Ad + r * 64 + ((((h << 2) | lq) ^ (r & 7)) << 3));
      }
      #pragma unroll
      for (int j = 0; j < 2; ++j) {
        const int r = (wave & 1) * 32 + j * 16 + l15;
        bf[j] = *(const bf16x8*)(Bd + r * 64 + ((((h << 2) | lq) ^ (r & 7)) << 3));
      }
      #pragma unroll
      for (int i = 0; i < 2; ++i)
        #pragma unroll
        for (int j = 0; j < 2; ++j)
          acc[i][j] = mfma16(af[i], bf[j], acc[i][j]);
    }
  };
  // degree fold (wave 0) + pipeline prologue; __syncthreads drains all & publishes sde
  if (t < 64) {
    const float* p = DePart + ((size_t)b * 1024 + e0 + t) * 32;
    float4 a0 = *(const float4*)(p + 0),  a1 = *(const float4*)(p + 4);
    float4 a2 = *(const float4*)(p + 8),  a3 = *(const float4*)(p + 12);
    float4 a4 = *(const float4*)(p + 16), a5 = *(const float4*)(p + 20);
    float4 a6 = *(const float4*)(p + 24), a7 = *(const float4*)(p + 28);
    float s = (((a0.x + a0.y) + (a0.z + a0.w)) + ((a1.x + a1.y) + (a1.z + a1.w)))
            + (((a2.x + a2.y) + (a2.z + a2.w)) + ((a3.x + a3.y) + (a3.z + a3.w)))
            + ((((a4.x + a4.y) + (a4.z + a4.w)) + ((a5.x + a5.y) + (a5.z + a5.w)))
            + (((a6.x + a6.y) + (a6.z + a6.w)) + ((a7.x + a7.y) + (a7.z + a7.w))));
    sde[t] = 1.f / (s + 1e-9f);
  }
  stage(As[0], Bs[0], 0);
  stage(As[1], Bs[1], 1);
  __syncthreads();
  const int NT = 32;
  uint16_t *cA = As[0], *nA = As[1], *fA = As[2];
  uint16_t *cB = Bs[0], *nB = Bs[1], *fB = Bs[2];
  for (int kt = 0; kt < NT - 2; ++kt) {
    stage(fA, fB, kt + 2);
    compute(cA, cB);
    PIPE_WAIT4();  // drain tile kt+1's loads; tile kt+2's stay in flight
    uint16_t* t1 = cA; cA = nA; nA = fA; fA = t1;
    uint16_t* t2 = cB; cB = nB; nB = fB; fB = t2;
  }
  compute(cA, cB);   // tile NT-2
  PIPE_WAIT0();      // drain tile NT-1's loads
  compute(nA, nB);   // tile NT-1
  #pragma unroll
  for (int i = 0; i < 2; ++i) {
    const int fr = f0 + (wave >> 1) * 32 + i * 16 + lq * 4;
    #pragma unroll
    for (int j = 0; j < 2; ++j) {
      const int el = (wave & 1) * 32 + j * 16 + l15;
      const float sc = sde[el];
      uint16_t* dst = Yt + ((size_t)b * 256 + fr) * 1024 + e0 + el;
      #pragma unroll
      for (int reg = 0; reg < 4; ++reg)
        dst[(size_t)reg * 1024] = f2b(acc[i][j][reg] * sc);
    }
  }
}

// ---- GEMM3: out[b][n][f] = relu( DvInv[b,n] * sum_e Hb[n][e]*Yt[f][e] ) ----
// tile 64n x 64f, K=1024 (NT=16). grid (32, 4, 8). same pipeline as gemm2.
__global__ __launch_bounds__(256) void k_gemm3(const uint16_t* __restrict__ Hb,
    const uint16_t* __restrict__ Yt, const float* __restrict__ DvPart,
    float* __restrict__ out) {
  __shared__ __align__(16) uint16_t As[3][64 * 64];
  __shared__ __align__(16) uint16_t Bs[3][64 * 64];
  __shared__ float sdv[64];
  const int n0 = blockIdx.x * 64, f0 = blockIdx.y * 64, b = blockIdx.z;
  const int t = threadIdx.x, lane = t & 63, wave = t >> 6;
  const int l15 = lane & 15, lq = lane >> 4;
  const int rlane = lane >> 3;
  const int srcswz = ((lane & 7) ^ rlane) << 3;
  const uint16_t* Ag = Hb + ((size_t)b * 2048 + n0) * 1024;
  const uint16_t* Bg = Yt + ((size_t)b * 256 + f0) * 1024;
  auto stage = [&](uint16_t* Ad, uint16_t* Bd, int kt) {  // 4 VMEM instrs/wave
    const int k0 = kt * 64;
    #pragma unroll
    for (int i = 0; i < 2; ++i) {
      const int r = wave * 16 + i * 8;
      gload16(Ag + (size_t)(r + rlane) * 1024 + k0 + srcswz, Ad + r * 64);
      gload16(Bg + (size_t)(r + rlane) * 1024 + k0 + srcswz, Bd + r * 64);
    }
  };
  f32x4 acc[2][2] = {};
  auto compute = [&](const uint16_t* Ad, const uint16_t* Bd) {
    #pragma unroll
    for (int h = 0; h < 2; ++h) {
      bf16x8 af[2], bf[2];
      #pragma unroll
      for (int i = 0; i < 2; ++i) {
        const int r = (wave >> 1) * 32 + i * 16 + l15;
        af[i] = *(const bf16x8*)(Ad + r * 64 + ((((h << 2) | lq) ^ (r & 7)) << 3));
      }
      #pragma unroll
      for (int j = 0; j < 2; ++j) {
        const int r = (wave & 1) * 32 + j * 16 + l15;
        bf[j] = *(const bf16x8*)(Bd + r * 64 + ((((h << 2) | lq) ^ (r & 7)) << 3));
      }
      #pragma unroll
      for (int i = 0; i < 2; ++i)
        #pragma unroll
        for (int j = 0; j < 2; ++j)
          acc[i][j] = mfma16(af[i], bf[j], acc[i][j]);
    }
  };
  if (t < 64) {
    float4 p = *(const float4*)(DvPart + ((size_t)b * 2048 + n0 + t) * 4);
    sdv[t] = 1.f / (((p.x + p.y) + (p.z + p.w)) + 1e-9f);
  }
  stage(As[0], Bs[0], 0);
  stage(As[1], Bs[1], 1);
  __syncthreads();
  const int NT = 16;
  uint16_t *cA = As[0], *nA = As[1], *fA = As[2];
  uint16_t *cB = Bs[0], *nB = Bs[1], *fB = Bs[2];
  for (int kt = 0; kt < NT - 2; ++kt) {
    stage(fA, fB, kt + 2);
    compute(cA, cB);
    PIPE_WAIT4();
    uint16_t* t1 = cA; cA = nA; nA = fA; fA = t1;
    uint16_t* t2 = cB; cB = nB; nB = fB; fB = t2;
  }
  compute(cA, cB);   // tile NT-2
  PIPE_WAIT0();
  compute(nA, nB);   // tile NT-1
  #pragma unroll
  for (int i = 0; i < 2; ++i) {
    const int nl = (wave >> 1) * 32 + i * 16 + lq * 4;
    #pragma unroll
    for (int reg = 0; reg < 4; ++reg) {
      const int row = n0 + nl + reg;
      const float sc = sdv[nl + reg];
      #pragma unroll
      for (int j = 0; j < 2; ++j) {
        const int col = f0 + (wave & 1) * 32 + j * 16 + l15;
        const float v = acc[i][j][reg] * sc;
        out[((size_t)b * 2048 + row) * 256 + col] = v > 0.f ? v : 0.f;
      }
    }
  }
}

extern "C" void kernel_launch(void* const* d_in, const int* in_sizes, int n_in,
                              void* d_out, int out_size, void* d_ws, size_t ws_size,
                              hipStream_t stream) {
  (void)in_sizes; (void)n_in; (void)out_size;
  const float* x = (const float*)d_in[0];   // [8,2048,256]
  const float* H = (const float*)d_in[1];   // [8,2048,1024]
  const float* W = (const float*)d_in[2];   // [256,256]
  float* out = (float*)d_out;               // [8,2048,256]

  // workspace layout (bytes):
  //   Hbt    bf16 [8,1024,2048] : 0        .. 33554432
  //   Hb     bf16 [8,2048,1024] : 33554432 .. 67108864
  //   XWt    bf16 [8,256,2048]  : 67108864 .. 75497472
  //   Yt     bf16 [8,256,1024]  : 75497472 .. 79691776
  //   DvPart f32  [8,2048,4]    : 79691776 .. 79953920
  //   DePart f32  [8,1024,32]   : 79953920 .. 81002496
  //   Wt     bf16 [256,256]     : 81002496 .. 81133568
  if (ws_size < 81133568) return;
  char* ws = (char*)d_ws;
  uint16_t* Hbt    = (uint16_t*)(ws);
  uint16_t* Hb     = (uint16_t*)(ws + 33554432);
  uint16_t* XWt    = (uint16_t*)(ws + 67108864);
  uint16_t* Yt     = (uint16_t*)(ws + 75497472);
  float*    DvPart = (float*)(ws + 79691776);
  float*    DePart = (float*)(ws + 79953920);
  uint16_t* Wt     = (uint16_t*)(ws + 81002496);

  k_prep_w<<<dim3(4, 4),     256, 0, stream>>>(W, Wt);
  k_prep_h<<<dim3(32, 4, 8), 256, 0, stream>>>(H, Hbt, Hb, DvPart, DePart);
  k_gemm1 <<<dim3(32, 2, 8), 256, 0, stream>>>(x, Wt, XWt);
  k_gemm2 <<<dim3(16, 4, 8), 256, 0, stream>>>(Hbt, XWt, DePart, Yt);
  k_gemm3 <<<dim3(32, 4, 8), 256, 0, stream>>>(Hb, Yt, DvPart, out);
}

// Round 8
// 79.368 us; speedup vs baseline: 2.3298x; 1.0041x over previous
//
#include <hip/hip_runtime.h>
#include <stdint.h>

// HypergraphConv: B=8, N=2048, E=1024, Fin=Fout=256, fp32 in/out.
// out = relu( Dv^-1 * H @ (De^-1 * (H^T @ (x@W))) )
// R8: prep_h split to 4096 single-subtile blocks (1 barrier, 16 blocks/CU)
// to fix its latency-bound regime. gemm2/gemm3 keep the R7 3-buffer depth-2
// counted-vmcnt pipeline. DvPart widened to 16 slots.

typedef __bf16 bf16x8 __attribute__((ext_vector_type(8)));
typedef float f32x4 __attribute__((ext_vector_type(4)));

#define PADK 72  // padded row stride (elems) for f32-reg-staged tiles

__device__ __forceinline__ uint16_t f2b(float f) {
  __bf16 h = (__bf16)f;
  return __builtin_bit_cast(uint16_t, h);
}

__device__ __forceinline__ f32x4 mfma16(bf16x8 a, bf16x8 b, f32x4 c) {
  return __builtin_amdgcn_mfma_f32_16x16x32_bf16(a, b, c, 0, 0, 0);
}

// async global->LDS, 16B/lane; LDS dest = uniform base + lane*16
__device__ __forceinline__ void gload16(const void* src, void* dst) {
  __builtin_amdgcn_global_load_lds(
      (const __attribute__((address_space(1))) void*)src,
      (__attribute__((address_space(3))) void*)dst, 16, 0, 0);
}

#define PIPE_WAIT4() do { \
    asm volatile("s_waitcnt vmcnt(4)" ::: "memory"); \
    __builtin_amdgcn_s_barrier(); \
    __builtin_amdgcn_sched_barrier(0); \
  } while (0)
#define PIPE_WAIT0() do { \
    asm volatile("s_waitcnt vmcnt(0)" ::: "memory"); \
    __builtin_amdgcn_s_barrier(); \
    __builtin_amdgcn_sched_barrier(0); \
  } while (0)

// ---- prep_w: Wt[f][k] = bf16(W[k][f]), 64x64 LDS transpose tiles ----
__global__ __launch_bounds__(256) void k_prep_w(const float* __restrict__ W,
    uint16_t* __restrict__ Wt) {
  __shared__ __align__(16) uint16_t T[64 * 68];
  const int k0 = blockIdx.x * 64, f0 = blockIdx.y * 64;
  const int t = threadIdx.x;
  const int r0 = (t >> 4) * 4, cc = (t & 15) * 4;
  float vv[4][4];
  #pragma unroll
  for (int i = 0; i < 4; ++i) {
    float4 q = *(const float4*)(W + (size_t)(k0 + r0 + i) * 256 + f0 + cc);
    vv[i][0] = q.x; vv[i][1] = q.y; vv[i][2] = q.z; vv[i][3] = q.w;
  }
  #pragma unroll
  for (int j = 0; j < 4; ++j) {
    union { uint16_t s[4]; uint2 u; } p;
    #pragma unroll
    for (int i = 0; i < 4; ++i) p.s[i] = f2b(vv[i][j]);
    *(uint2*)&T[(cc + j) * 68 + r0] = p.u;
  }
  __syncthreads();
  const int er = t >> 2, c2 = (t & 3) * 16;
  union { uint16_t s[16]; uint4 q[2]; } o;
  #pragma unroll
  for (int m = 0; m < 4; ++m)
    *(uint2*)&o.s[m * 4] = *(const uint2*)&T[er * 68 + c2 + m * 4];
  uint16_t* dst = Wt + (size_t)(f0 + er) * 256 + k0 + c2;
  *(uint4*)dst = o.q[0];
  *(uint4*)(dst + 8) = o.q[1];
}

// ---- prep_h: Hbt[e][n], Hb[n][e] bf16; Dv/De partials (no atomics) ----
// block: one 64n x 64e tile, ONE barrier. grid (32, 16, 8) = 4096 blocks.
__global__ __launch_bounds__(256) void k_prep_h(const float* __restrict__ H,
    uint16_t* __restrict__ Hbt, uint16_t* __restrict__ Hb,
    float* __restrict__ DvPart, float* __restrict__ DePart) {
  __shared__ __align__(16) uint16_t T[64 * 68];
  __shared__ float cs[4][64];
  const int n0 = blockIdx.x * 64, e0 = blockIdx.y * 64, b = blockIdx.z;
  const int t = threadIdx.x, lane = t & 63, wave = t >> 6;
  const int r0 = (t >> 4) * 4;   // first of 4 consecutive n-rows
  const int cc = (t & 15) * 4;   // first of 4 e-cols
  float vv[4][4];
  float dv[4];
  float de0 = 0.f, de1 = 0.f, de2 = 0.f, de3 = 0.f;
  #pragma unroll
  for (int i = 0; i < 4; ++i) {
    float4 q = *(const float4*)(H + ((size_t)b * 2048 + n0 + r0 + i) * 1024 + e0 + cc);
    vv[i][0] = q.x; vv[i][1] = q.y; vv[i][2] = q.z; vv[i][3] = q.w;
    float rs = (q.x + q.y) + (q.z + q.w);
    rs += __shfl_xor(rs, 1); rs += __shfl_xor(rs, 2);
    rs += __shfl_xor(rs, 4); rs += __shfl_xor(rs, 8);
    dv[i] = rs;
    de0 += q.x; de1 += q.y; de2 += q.z; de3 += q.w;
  }
  // row-major bf16 copy for gemm3 (coalesced 8B stores)
  #pragma unroll
  for (int i = 0; i < 4; ++i) {
    union { uint16_t s[4]; uint2 u; } p;
    #pragma unroll
    for (int j = 0; j < 4; ++j) p.s[j] = f2b(vv[i][j]);
    *(uint2*)(Hb + ((size_t)b * 2048 + n0 + r0 + i) * 1024 + e0 + cc) = p.u;
  }
  // transposed LDS write: per e-col j, 4 consecutive n as one b64
  #pragma unroll
  for (int j = 0; j < 4; ++j) {
    union { uint16_t s[4]; uint2 u; } p;
    #pragma unroll
    for (int i = 0; i < 4; ++i) p.s[i] = f2b(vv[i][j]);
    *(uint2*)&T[(cc + j) * 68 + r0] = p.u;
  }
  // De partials: reduce over the wave's 16 rows via xor-16/32
  de0 += __shfl_xor(de0, 16); de0 += __shfl_xor(de0, 32);
  de1 += __shfl_xor(de1, 16); de1 += __shfl_xor(de1, 32);
  de2 += __shfl_xor(de2, 16); de2 += __shfl_xor(de2, 32);
  de3 += __shfl_xor(de3, 16); de3 += __shfl_xor(de3, 32);
  if (lane < 16) *(float4*)&cs[wave][cc] = make_float4(de0, de1, de2, de3);
  // Dv partials (one writer per 16-lane group)
  if ((lane & 15) == 0) {
    #pragma unroll
    for (int i = 0; i < 4; ++i)
      DvPart[((size_t)b * 2048 + n0 + r0 + i) * 16 + blockIdx.y] = dv[i];
  }
  __syncthreads();
  // transposed read + coalesced global store: thread -> row e, 16-n chunk
  const int er = t >> 2, c2 = (t & 3) * 16;
  union { uint16_t s[16]; uint4 q[2]; } o;
  #pragma unroll
  for (int m = 0; m < 4; ++m)
    *(uint2*)&o.s[m * 4] = *(const uint2*)&T[er * 68 + c2 + m * 4];
  uint16_t* dst = Hbt + ((size_t)b * 1024 + e0 + er) * 2048 + n0 + c2;
  *(uint4*)dst = o.q[0];
  *(uint4*)(dst + 8) = o.q[1];
  if (t < 64) {
    float s = (cs[0][t] + cs[1][t]) + (cs[2][t] + cs[3][t]);
    DePart[((size_t)b * 1024 + e0 + t) * 32 + blockIdx.x] = s;  // [b][e][32]
  }
}

// ---- GEMM1: XWt[b][f][n] = bf16( sum_k Wt[f][k] * x[b][n][k] ) ----
// tile 128f x 64n, K=256, BK=64. grid (32, 2, 8).
__global__ __launch_bounds__(256) void k_gemm1(const float* __restrict__ X,
    const uint16_t* __restrict__ Wt, uint16_t* __restrict__ XWt) {
  __shared__ __align__(16) uint16_t As[2][128 * 64];  // Wt, gload_lds + XOR swz
  __shared__ __align__(16) uint16_t Bs[2][64 * PADK]; // x, f32 reg-staged, padded
  const int n0 = blockIdx.x * 64, f0 = blockIdx.y * 128, b = blockIdx.z;
  const int t = threadIdx.x, lane = t & 63, wave = t >> 6;
  const int l15 = lane & 15, lq = lane >> 4;
  const int rlane = lane >> 3;
  const int srcswz = ((lane & 7) ^ rlane) << 3;
  const uint16_t* Ag = Wt + (size_t)f0 * 256;
  const int br = t >> 2, kc = (t & 3) * 16;
  const float* Xg = X + ((size_t)b * 2048 + n0 + br) * 256 + kc;
  float4 RX[4];
  auto stageA = [&](uint16_t* Ad, int kt) {
    const int k0 = kt * 64;
    #pragma unroll
    for (int i = 0; i < 4; ++i) {
      const int r = wave * 32 + i * 8;
      gload16(Ag + (size_t)(r + rlane) * 256 + k0 + srcswz, Ad + r * 64);
    }
  };
  auto gloadB = [&](int kt) {
    const float* s = Xg + kt * 64;
    #pragma unroll
    for (int q = 0; q < 4; ++q) RX[q] = *(const float4*)(s + q * 4);
  };
  auto writeB = [&](uint16_t* Bd) {
    uint16_t* d = Bd + br * PADK + kc;
    const float* f = (const float*)RX;
    #pragma unroll
    for (int q = 0; q < 2; ++q) {
      union { uint16_t s[8]; uint4 u; } p;
      #pragma unroll
      for (int j = 0; j < 8; ++j) p.s[j] = f2b(f[q * 8 + j]);
      *(uint4*)(d + q * 8) = p.u;
    }
  };
  f32x4 acc[4][2] = {};
  auto compute = [&](const uint16_t* Ad, const uint16_t* Bd) {
    #pragma unroll
    for (int h = 0; h < 2; ++h) {
      bf16x8 af[4], bf[2];
      #pragma unroll
      for (int i = 0; i < 4; ++i) {
        const int r = (wave >> 1) * 64 + i * 16 + l15;
        af[i] = *(const bf16x8*)(Ad + r * 64 + ((((h << 2) | lq) ^ (r & 7)) << 3));
      }
      #pragma unroll
      for (int j = 0; j < 2; ++j) {
        const int r = (wave & 1) * 32 + j * 16 + l15;
        bf[j] = *(const bf16x8*)(Bd + r * PADK + h * 32 + lq * 8);
      }
      #pragma unroll
      for (int i = 0; i < 4; ++i)
        #pragma unroll
        for (int j = 0; j < 2; ++j)
          acc[i][j] = mfma16(af[i], bf[j], acc[i][j]);
    }
  };
  stageA(As[0], 0); gloadB(0); writeB(Bs[0]);
  __syncthreads();
  for (int kt = 0; kt < 4; kt += 2) {
    stageA(As[1], kt + 1); gloadB(kt + 1);
    compute(As[0], Bs[0]);
    writeB(Bs[1]);
    __syncthreads();
    if (kt + 2 < 4) { stageA(As[0], kt + 2); gloadB(kt + 2); }
    compute(As[1], Bs[1]);
    if (kt + 2 < 4) writeB(Bs[0]);
    __syncthreads();
  }
  #pragma unroll
  for (int i = 0; i < 4; ++i) {
    const int fr = f0 + (wave >> 1) * 64 + i * 16 + lq * 4;
    #pragma unroll
    for (int j = 0; j < 2; ++j) {
      const int col = n0 + (wave & 1) * 32 + j * 16 + l15;
      #pragma unroll
      for (int reg = 0; reg < 4; ++reg)
        XWt[((size_t)b * 256 + fr + reg) * 2048 + col] = f2b(acc[i][j][reg]);
    }
  }
}

// ---- GEMM2: Yt[b][f][e] = bf16( DeInv[b,e] * sum_n XWt[f][n]*Hbt[e][n] ) ----
// tile 64f x 64e, K=2048 (NT=32). grid (16, 4, 8). depth-2 pipeline, vmcnt(4).
__global__ __launch_bounds__(256) void k_gemm2(const uint16_t* __restrict__ Hbt,
    const uint16_t* __restrict__ XWt, const float* __restrict__ DePart,
    uint16_t* __restrict__ Yt) {
  __shared__ __align__(16) uint16_t As[3][64 * 64];
  __shared__ __align__(16) uint16_t Bs[3][64 * 64];
  __shared__ float sde[64];
  const int e0 = blockIdx.x * 64, f0 = blockIdx.y * 64, b = blockIdx.z;
  const int t = threadIdx.x, lane = t & 63, wave = t >> 6;
  const int l15 = lane & 15, lq = lane >> 4;
  const int rlane = lane >> 3;
  const int srcswz = ((lane & 7) ^ rlane) << 3;
  const uint16_t* Ag = XWt + ((size_t)b * 256 + f0) * 2048;
  const uint16_t* Bg = Hbt + ((size_t)b * 1024 + e0) * 2048;
  auto stage = [&](uint16_t* Ad, uint16_t* Bd, int kt) {  // 4 VMEM instrs/wave
    const int k0 = kt * 64;
    #pragma unroll
    for (int i = 0; i < 2; ++i) {
      const int r = wave * 16 + i * 8;
      gload16(Ag + (size_t)(r + rlane) * 2048 + k0 + srcswz, Ad + r * 64);
      gload16(Bg + (size_t)(r + rlane) * 2048 + k0 + srcswz, Bd + r * 64);
    }
  };
  f32x4 acc[2][2] = {};
  auto compute = [&](const uint16_t* Ad, const uint16_t* Bd) {
    #pragma unroll
    for (int h = 0; h < 2; ++h) {
      bf16x8 af[2], bf[2];
      #pragma unroll
      for (int i = 0; i < 2; ++i) {
        const int r = (wave >> 1) * 32 + i * 16 + l15;
        af[i] = *(const bf16x8*)(Ad + r * 64 + ((((h << 2) | lq) ^ (r & 7)) << 3));
      }
      #pragma unroll
      for (int j = 0; j < 2; ++j) {
        const int r = (wave & 1) * 32 + j * 16 + l15;
        bf[j] = *(const bf16x8*)(Bd + r * 64 + ((((h << 2) | lq) ^ (r & 7)) << 3));
      }
      #pragma unroll
      for (int i = 0; i < 2; ++i)
        #pragma unroll
        for (int j = 0; j < 2; ++j)
          acc[i][j] = mfma16(af[i], bf[j], acc[i][j]);
    }
  };
  if (t < 64) {
    const float* p = DePart + ((size_t)b * 1024 + e0 + t) * 32;
    float4 a0 = *(const float4*)(p + 0),  a1 = *(const float4*)(p + 4);
    float4 a2 = *(const float4*)(p + 8),  a3 = *(const float4*)(p + 12);
    float4 a4 = *(const float4*)(p + 16), a5 = *(const float4*)(p + 20);
    float4 a6 = *(const float4*)(p + 24), a7 = *(const float4*)(p + 28);
    float s = (((a0.x + a0.y) + (a0.z + a0.w)) + ((a1.x + a1.y) + (a1.z + a1.w)))
            + (((a2.x + a2.y) + (a2.z + a2.w)) + ((a3.x + a3.y) + (a3.z + a3.w)))
            + ((((a4.x + a4.y) + (a4.z + a4.w)) + ((a5.x + a5.y) + (a5.z + a5.w)))
            + (((a6.x + a6.y) + (a6.z + a6.w)) + ((a7.x + a7.y) + (a7.z + a7.w))));
    sde[t] = 1.f / (s + 1e-9f);
  }
  stage(As[0], Bs[0], 0);
  stage(As[1], Bs[1], 1);
  __syncthreads();
  const int NT = 32;
  uint16_t *cA = As[0], *nA = As[1], *fA = As[2];
  uint16_t *cB = Bs[0], *nB = Bs[1], *fB = Bs[2];
  for (int kt = 0; kt < NT - 2; ++kt) {
    stage(fA, fB, kt + 2);
    compute(cA, cB);
    PIPE_WAIT4();  // drain tile kt+1's loads; tile kt+2's stay in flight
    uint16_t* t1 = cA; cA = nA; nA = fA; fA = t1;
    uint16_t* t2 = cB; cB = nB; nB = fB; fB = t2;
  }
  compute(cA, cB);   // tile NT-2
  PIPE_WAIT0();      // drain tile NT-1's loads
  compute(nA, nB);   // tile NT-1
  #pragma unroll
  for (int i = 0; i < 2; ++i) {
    const int fr = f0 + (wave >> 1) * 32 + i * 16 + lq * 4;
    #pragma unroll
    for (int j = 0; j < 2; ++j) {
      const int el = (wave & 1) * 32 + j * 16 + l15;
      const float sc = sde[el];
      uint16_t* dst = Yt + ((size_t)b * 256 + fr) * 1024 + e0 + el;
      #pragma unroll
      for (int reg = 0; reg < 4; ++reg)
        dst[(size_t)reg * 1024] = f2b(acc[i][j][reg] * sc);
    }
  }
}

// ---- GEMM3: out[b][n][f] = relu( DvInv[b,n] * sum_e Hb[n][e]*Yt[f][e] ) ----
// tile 64n x 64f, K=1024 (NT=16). grid (32, 4, 8). same pipeline as gemm2.
__global__ __launch_bounds__(256) void k_gemm3(const uint16_t* __restrict__ Hb,
    const uint16_t* __restrict__ Yt, const float* __restrict__ DvPart,
    float* __restrict__ out) {
  __shared__ __align__(16) uint16_t As[3][64 * 64];
  __shared__ __align__(16) uint16_t Bs[3][64 * 64];
  __shared__ float sdv[64];
  const int n0 = blockIdx.x * 64, f0 = blockIdx.y * 64, b = blockIdx.z;
  const int t = threadIdx.x, lane = t & 63, wave = t >> 6;
  const int l15 = lane & 15, lq = lane >> 4;
  const int rlane = lane >> 3;
  const int srcswz = ((lane & 7) ^ rlane) << 3;
  const uint16_t* Ag = Hb + ((size_t)b * 2048 + n0) * 1024;
  const uint16_t* Bg = Yt + ((size_t)b * 256 + f0) * 1024;
  auto stage = [&](uint16_t* Ad, uint16_t* Bd, int kt) {  // 4 VMEM instrs/wave
    const int k0 = kt * 64;
    #pragma unroll
    for (int i = 0; i < 2; ++i) {
      const int r = wave * 16 + i * 8;
      gload16(Ag + (size_t)(r + rlane) * 1024 + k0 + srcswz, Ad + r * 64);
      gload16(Bg + (size_t)(r + rlane) * 1024 + k0 + srcswz, Bd + r * 64);
    }
  };
  f32x4 acc[2][2] = {};
  auto compute = [&](const uint16_t* Ad, const uint16_t* Bd) {
    #pragma unroll
    for (int h = 0; h < 2; ++h) {
      bf16x8 af[2], bf[2];
      #pragma unroll
      for (int i = 0; i < 2; ++i) {
        const int r = (wave >> 1) * 32 + i * 16 + l15;
        af[i] = *(const bf16x8*)(Ad + r * 64 + ((((h << 2) | lq) ^ (r & 7)) << 3));
      }
      #pragma unroll
      for (int j = 0; j < 2; ++j) {
        const int r = (wave & 1) * 32 + j * 16 + l15;
        bf[j] = *(const bf16x8*)(Bd + r * 64 + ((((h << 2) | lq) ^ (r & 7)) << 3));
      }
      #pragma unroll
      for (int i = 0; i < 2; ++i)
        #pragma unroll
        for (int j = 0; j < 2; ++j)
          acc[i][j] = mfma16(af[i], bf[j], acc[i][j]);
    }
  };
  if (t < 64) {
    const float* p = DvPart + ((size_t)b * 2048 + n0 + t) * 16;
    float4 a0 = *(const float4*)(p + 0),  a1 = *(const float4*)(p + 4);
    float4 a2 = *(const float4*)(p + 8),  a3 = *(const float4*)(p + 12);
    float s = (((a0.x + a0.y) + (a0.z + a0.w)) + ((a1.x + a1.y) + (a1.z + a1.w)))
            + (((a2.x + a2.y) + (a2.z + a2.w)) + ((a3.x + a3.y) + (a3.z + a3.w)));
    sdv[t] = 1.f / (s + 1e-9f);
  }
  stage(As[0], Bs[0], 0);
  stage(As[1], Bs[1], 1);
  __syncthreads();
  const int NT = 16;
  uint16_t *cA = As[0], *nA = As[1], *fA = As[2];
  uint16_t *cB = Bs[0], *nB = Bs[1], *fB = Bs[2];
  for (int kt = 0; kt < NT - 2; ++kt) {
    stage(fA, fB, kt + 2);
    compute(cA, cB);
    PIPE_WAIT4();
    uint16_t* t1 = cA; cA = nA; nA = fA; fA = t1;
    uint16_t* t2 = cB; cB = nB; nB = fB; fB = t2;
  }
  compute(cA, cB);   // tile NT-2
  PIPE_WAIT0();
  compute(nA, nB);   // tile NT-1
  #pragma unroll
  for (int i = 0; i < 2; ++i) {
    const int nl = (wave >> 1) * 32 + i * 16 + lq * 4;
    #pragma unroll
    for (int reg = 0; reg < 4; ++reg) {
      const int row = n0 + nl + reg;
      const float sc = sdv[nl + reg];
      #pragma unroll
      for (int j = 0; j < 2; ++j) {
        const int col = f0 + (wave & 1) * 32 + j * 16 + l15;
        const float v = acc[i][j][reg] * sc;
        out[((size_t)b * 2048 + row) * 256 + col] = v > 0.f ? v : 0.f;
      }
    }
  }
}

extern "C" void kernel_launch(void* const* d_in, const int* in_sizes, int n_in,
                              void* d_out, int out_size, void* d_ws, size_t ws_size,
                              hipStream_t stream) {
  (void)in_sizes; (void)n_in; (void)out_size;
  const float* x = (const float*)d_in[0];   // [8,2048,256]
  const float* H = (const float*)d_in[1];   // [8,2048,1024]
  const float* W = (const float*)d_in[2];   // [256,256]
  float* out = (float*)d_out;               // [8,2048,256]

  // workspace layout (bytes):
  //   Hbt    bf16 [8,1024,2048] : 0        .. 33554432
  //   Hb     bf16 [8,2048,1024] : 33554432 .. 67108864
  //   XWt    bf16 [8,256,2048]  : 67108864 .. 75497472
  //   Yt     bf16 [8,256,1024]  : 75497472 .. 79691776
  //   DvPart f32  [8,2048,16]   : 79691776 .. 80740352
  //   DePart f32  [8,1024,32]   : 80740352 .. 81788928
  //   Wt     bf16 [256,256]     : 81788928 .. 81920000
  if (ws_size < 81920000) return;
  char* ws = (char*)d_ws;
  uint16_t* Hbt    = (uint16_t*)(ws);
  uint16_t* Hb     = (uint16_t*)(ws + 33554432);
  uint16_t* XWt    = (uint16_t*)(ws + 67108864);
  uint16_t* Yt     = (uint16_t*)(ws + 75497472);
  float*    DvPart = (float*)(ws + 79691776);
  float*    DePart = (float*)(ws + 80740352);
  uint16_t* Wt     = (uint16_t*)(ws + 81788928);

  k_prep_w<<<dim3(4, 4),      256, 0, stream>>>(W, Wt);
  k_prep_h<<<dim3(32, 16, 8), 256, 0, stream>>>(H, Hbt, Hb, DvPart, DePart);
  k_gemm1 <<<dim3(32, 2, 8),  256, 0, stream>>>(x, Wt, XWt);
  k_gemm2 <<<dim3(16, 4, 8),  256, 0, stream>>>(Hbt, XWt, DePart, Yt);
  k_gemm3 <<<dim3(32, 4, 8),  256, 0, stream>>>(Hb, Yt, DvPart, out);
}